// Round 5
// baseline (960.955 us; speedup 1.0000x reference)
//
#include <hip/hip_runtime.h>
#include <hip/hip_bf16.h>
#include <math.h>

typedef unsigned short ushort_t;
typedef __attribute__((ext_vector_type(8))) short bf16x8;   // 8 bf16 = 4 VGPRs
typedef __attribute__((ext_vector_type(4))) float f32x4;

#define SCALE_QK 0.04419417382415922f   // 1/sqrt(512)
#define PE_C 0.017988946039015986f      // ln(10000)/512

// ---------------------------------------------------------------------------
__device__ __forceinline__ void g2lds16(const void* g, void* l) {
    __builtin_amdgcn_global_load_lds(
        (const __attribute__((address_space(1))) unsigned int*)g,
        (__attribute__((address_space(3))) unsigned int*)l,
        16, 0, 0);
}
__device__ __forceinline__ ushort_t f2bs(float v) {
    __hip_bfloat16 h = __float2bfloat16(v);
    return *reinterpret_cast<ushort_t*>(&h);
}
__device__ __forceinline__ float bs2f(ushort_t v) {
    return __uint_as_float(((unsigned int)v) << 16);
}

// ---------------------------------------------------------------------------
// 256x256 / 8-wave GEMM with counted-vmcnt cross-barrier pipeline.
// Wave-tile 128x64 (MI=8,NJ=4). LDS double-buffer 128 KiB; loads for tile
// kt+2 issued after a RAW barrier and waited with vmcnt(8) -- 8 loads stay
// in flight across every barrier (never drain to 0 mid-loop).
template<bool RELU, bool VT>
__global__ __launch_bounds__(512, 2) void gemm8(
    const ushort_t* __restrict__ A, const ushort_t* __restrict__ B,
    const float* __restrict__ bias, ushort_t* __restrict__ C,
    ushort_t* __restrict__ vt, int K, int lda, int ldb, int ldc)
{
    __shared__ ushort_t As[2][256 * 64];
    __shared__ ushort_t Bs[2][256 * 64];

    const int t = threadIdx.x;
    const int lane = t & 63, w = t >> 6;        // 8 waves
    const int l16 = lane & 15, quad = lane >> 4;
    const int r8 = lane >> 3;
    const int kg = ((lane & 7) ^ r8) << 3;      // swizzled global k-chunk
    const int wm = (w >> 2) * 128;              // 2 wave-rows (M)
    const int wn = (w & 3) * 64;                // 4 wave-cols (N)
    const int m0 = blockIdx.y * 256, n0 = blockIdx.x * 256;
    const int NT = K >> 6;

    f32x4 acc[8][4];
    #pragma unroll
    for (int i = 0; i < 8; i++)
        #pragma unroll
        for (int j = 0; j < 4; j++)
            acc[i][j] = (f32x4){0.f, 0.f, 0.f, 0.f};

    auto STAGE8 = [&](int kt, int bb) {
        int k0 = kt << 6;
        #pragma unroll
        for (int ii = 0; ii < 4; ii++) {        // 8 waves x 32 rows = 256
            int rbase = w * 32 + ii * 8;
            g2lds16(A + (size_t)(m0 + rbase + r8) * lda + k0 + kg,
                    &As[bb][rbase * 64]);
            g2lds16(B + (size_t)(n0 + rbase + r8) * ldb + k0 + kg,
                    &Bs[bb][rbase * 64]);
        }
    };

    STAGE8(0, 0);
    STAGE8(1, 1);

    for (int kt = 0; kt < NT; kt++) {
        const int bb = kt & 1;
        if (kt < NT - 1)
            asm volatile("s_waitcnt vmcnt(8)" ::: "memory");
        else
            asm volatile("s_waitcnt vmcnt(0)" ::: "memory");
        __builtin_amdgcn_s_barrier();           // all waves confirmed tile kt
        asm volatile("" ::: "memory");

        #pragma unroll
        for (int tt = 0; tt < 2; tt++) {
            bf16x8 af[8], bf[4];
            #pragma unroll
            for (int i = 0; i < 8; i++) {
                int row = wm + i * 16 + l16;
                af[i] = *(const bf16x8*)&As[bb][row * 64 + ((((tt << 2) + quad) ^ (row & 7)) << 3)];
            }
            #pragma unroll
            for (int j = 0; j < 4; j++) {
                int row = wn + j * 16 + l16;
                bf[j] = *(const bf16x8*)&Bs[bb][row * 64 + ((((tt << 2) + quad) ^ (row & 7)) << 3)];
            }
            #pragma unroll
            for (int i = 0; i < 8; i++)
                #pragma unroll
                for (int j = 0; j < 4; j++)
                    acc[i][j] = __builtin_amdgcn_mfma_f32_16x16x32_bf16(
                        af[i], bf[j], acc[i][j], 0, 0, 0);
        }

        asm volatile("" ::: "memory");
        __builtin_amdgcn_s_barrier();
        asm volatile("" ::: "memory");
        if (kt + 2 < NT)
            STAGE8(kt + 2, bb);
    }

    // ---- epilogue ----
    if (VT && n0 >= 1024) {
        #pragma unroll
        for (int i = 0; i < 8; i++) {
            int mbase = m0 + wm + i * 16 + quad * 4;
            int b = mbase >> 9, s = mbase & 511;
            #pragma unroll
            for (int j = 0; j < 4; j++) {
                int n = n0 + wn + j * 16 + l16;
                int hv = n - 1024;
                int h = hv >> 6, vd = hv & 63;
                float bv = bias[n];
                ushort4 pk;
                pk.x = f2bs(acc[i][j][0] + bv);
                pk.y = f2bs(acc[i][j][1] + bv);
                pk.z = f2bs(acc[i][j][2] + bv);
                pk.w = f2bs(acc[i][j][3] + bv);
                *(ushort4*)&vt[((size_t)((b << 3) + h)) * 32768 + (size_t)vd * 512 + s] = pk;
            }
        }
        return;
    }

    #pragma unroll
    for (int i = 0; i < 8; i++)
        #pragma unroll
        for (int j = 0; j < 4; j++) {
            int n = n0 + wn + j * 16 + l16;
            float bv = bias[n];
            #pragma unroll
            for (int r = 0; r < 4; r++) {
                int m = m0 + wm + i * 16 + quad * 4 + r;
                float v = acc[i][j][r] + bv;
                if (RELU) v = fmaxf(v, 0.f);
                C[(size_t)m * ldc + n] = f2bs(v);
            }
        }
}

// ---------------------------------------------------------------------------
// 128x128 / 4-wave GEMM, 2 blocks/CU (64 KB LDS): same counted-vmcnt
// pipeline as gemm8 (per-wave 8 loads/tile -> vmcnt(8)); wave-tile 64x64
// (MI=4,NJ=4) keeps MFMA(160cy) ~ ds_read(192cy) balanced, and the sibling
// block covers this block's barrier/vmcnt stalls. Epilogue: bias + residual
// + bf16 C + LN stat partials (sum,sumsq per 64-col slice) to
// part[m*8 + bx*2 + (w&1)]. Replaces gemmLN (whose 32x64 wave-tile was
// LDS-fragment-read-bound at ~350 TF).
__global__ __launch_bounds__(256, 2) void gemm4(
    const ushort_t* __restrict__ A, const ushort_t* __restrict__ B,
    const float* __restrict__ bias, const ushort_t* __restrict__ resb,
    ushort_t* __restrict__ C, float2* __restrict__ part,
    int K, int lda, int ldb, int ldc)
{
    __shared__ ushort_t As[2][128 * 64];
    __shared__ ushort_t Bs[2][128 * 64];

    const int t = threadIdx.x;
    const int lane = t & 63, w = t >> 6;        // 4 waves
    const int l16 = lane & 15, quad = lane >> 4;
    const int r8 = lane >> 3;
    const int kg = ((lane & 7) ^ r8) << 3;
    const int wm = (w >> 1) * 64;
    const int wn = (w & 1) * 64;
    const int m0 = blockIdx.y * 128, n0 = blockIdx.x * 128;
    const int NT = K >> 6;

    f32x4 acc[4][4];
    #pragma unroll
    for (int i = 0; i < 4; i++)
        #pragma unroll
        for (int j = 0; j < 4; j++)
            acc[i][j] = (f32x4){0.f, 0.f, 0.f, 0.f};

    auto STAGE = [&](int kt, int bb) {
        int k0 = kt << 6;
        #pragma unroll
        for (int ii = 0; ii < 4; ii++) {        // 4 waves x 32 rows = 128
            int rbase = w * 32 + ii * 8;
            g2lds16(A + (size_t)(m0 + rbase + r8) * lda + k0 + kg,
                    &As[bb][rbase * 64]);
            g2lds16(B + (size_t)(n0 + rbase + r8) * ldb + k0 + kg,
                    &Bs[bb][rbase * 64]);
        }
    };

    STAGE(0, 0);
    STAGE(1, 1);

    for (int kt = 0; kt < NT; kt++) {
        const int bb = kt & 1;
        if (kt < NT - 1)
            asm volatile("s_waitcnt vmcnt(8)" ::: "memory");
        else
            asm volatile("s_waitcnt vmcnt(0)" ::: "memory");
        __builtin_amdgcn_s_barrier();
        asm volatile("" ::: "memory");

        #pragma unroll
        for (int tt = 0; tt < 2; tt++) {
            bf16x8 af[4], bf[4];
            #pragma unroll
            for (int i = 0; i < 4; i++) {
                int row = wm + i * 16 + l16;
                af[i] = *(const bf16x8*)&As[bb][row * 64 + ((((tt << 2) + quad) ^ (row & 7)) << 3)];
            }
            #pragma unroll
            for (int j = 0; j < 4; j++) {
                int row = wn + j * 16 + l16;
                bf[j] = *(const bf16x8*)&Bs[bb][row * 64 + ((((tt << 2) + quad) ^ (row & 7)) << 3)];
            }
            #pragma unroll
            for (int i = 0; i < 4; i++)
                #pragma unroll
                for (int j = 0; j < 4; j++)
                    acc[i][j] = __builtin_amdgcn_mfma_f32_16x16x32_bf16(
                        af[i], bf[j], acc[i][j], 0, 0, 0);
        }

        asm volatile("" ::: "memory");
        __builtin_amdgcn_s_barrier();
        asm volatile("" ::: "memory");
        if (kt + 2 < NT)
            STAGE(kt + 2, bb);
    }

    // ---- epilogue: bias + residual + stats ----
    #pragma unroll
    for (int i = 0; i < 4; i++) {
        float rs[4] = {0.f, 0.f, 0.f, 0.f}, rq[4] = {0.f, 0.f, 0.f, 0.f};
        #pragma unroll
        for (int j = 0; j < 4; j++) {
            int n = n0 + wn + j * 16 + l16;
            float bv = bias[n];
            #pragma unroll
            for (int r = 0; r < 4; r++) {
                int m = m0 + wm + i * 16 + quad * 4 + r;
                float v = acc[i][j][r] + bv + bs2f(resb[(size_t)m * ldc + n]);
                C[(size_t)m * ldc + n] = f2bs(v);
                rs[r] += v; rq[r] += v * v;
            }
        }
        #pragma unroll
        for (int r = 0; r < 4; r++) {
            float s = rs[r], q = rq[r];
            #pragma unroll
            for (int off = 1; off < 16; off <<= 1) {
                s += __shfl_xor(s, off);
                q += __shfl_xor(q, off);
            }
            if (l16 == 0) {
                int m = m0 + wm + i * 16 + quad * 4 + r;
                part[(size_t)m * 8 + blockIdx.x * 2 + (w & 1)] = make_float2(s, q);
            }
        }
    }
}

// ---------------------------------------------------------------------------
// LN from fused stats: part[row][8] float2 partial (sum,sumsq); Cpre bf16.
__global__ __launch_bounds__(256) void ln_stats(const ushort_t* __restrict__ Cpre,
                                                const float2* __restrict__ part,
                                                const float* __restrict__ g,
                                                const float* __restrict__ b,
                                                ushort_t* __restrict__ Xb) {
    long long row = blockIdx.x;
    int t = threadIdx.x;
    float s = 0.f, q = 0.f;
    if (t < 8) {
        float2 p = part[row * 8 + t];
        s = p.x; q = p.y;
    }
    #pragma unroll
    for (int off = 1; off < 8; off <<= 1) {
        s += __shfl_xor(s, off);
        q += __shfl_xor(q, off);
    }
    __shared__ float mv[2];
    if (t == 0) {
        float mean = s * (1.f / 512.f);
        float var = q * (1.f / 512.f) - mean * mean;
        mv[0] = mean;
        mv[1] = rsqrtf(var + 1e-5f);
    }
    __syncthreads();
    float mean = mv[0], r = mv[1];
    int c = t * 2;
    ushort2 u = *(const ushort2*)&Cpre[row * 512 + c];
    ushort2 o;
    o.x = f2bs((bs2f(u.x) - mean) * r * g[c]     + b[c]);
    o.y = f2bs((bs2f(u.y) - mean) * r * g[c + 1] + b[c + 1]);
    *(ushort2*)&Xb[row * 512 + c] = o;
}

// ---------------------------------------------------------------------------
// Fused flash attention: one (b,h), 128 q rows/block, 4 key-chunks of 128,
// fixed softmax reference m=0, ctx in-place into Q slice.
// LDS 64 KB (Ks unioned into Ps lo-half, +1 barrier between QK and P-write)
// -> 2 blocks/CU guaranteed.
__global__ __launch_bounds__(256) void flash_attn(
    ushort_t* __restrict__ QKV, const ushort_t* __restrict__ Vt,
    const int* __restrict__ tok)
{
    __shared__ ushort_t Qs[128 * 64];           // 16 KB
    __shared__ ushort_t Ps[128 * 128];          // 32 KB; lo 16 KB doubles as Ks
    __shared__ ushort_t Vts[64 * 128];          // 16 KB
    ushort_t* Ks = Ps;                          // union: K-tile lives in Ps lo

    const int bh = blockIdx.y;
    const int b = bh >> 3, h = bh & 7;
    const int q0 = blockIdx.x * 128;
    const int t = threadIdx.x;
    const int lane = t & 63, w = t >> 6;
    const int l16 = lane & 15, quad = lane >> 4;
    const int wm = w * 32;
    const size_t rowbase = (size_t)b * 512;

    {
        int r8 = lane >> 3;
        int kg = (lane & 7) ^ r8;
        #pragma unroll
        for (int ii = 0; ii < 4; ii++) {
            int rb = w * 32 + ii * 8;
            g2lds16(QKV + (rowbase + q0 + rb + r8) * 1536 + h * 64 + kg * 8,
                    &Qs[rb * 64]);
        }
    }

    f32x4 accO[2][4];
    #pragma unroll
    for (int i = 0; i < 2; i++)
        #pragma unroll
        for (int jv = 0; jv < 4; jv++)
            accO[i][jv] = (f32x4){0.f, 0.f, 0.f, 0.f};
    float lrow[2][4];
    #pragma unroll
    for (int i = 0; i < 2; i++)
        #pragma unroll
        for (int r = 0; r < 4; r++) lrow[i][r] = 0.f;

    for (int kc = 0; kc < 4; kc++) {
        __syncthreads();                        // prev PV reads of Ps/Vts done
        {
            int r8 = lane >> 3;
            int kg = (lane & 7) ^ r8;
            #pragma unroll
            for (int ii = 0; ii < 4; ii++) {
                int rb = w * 32 + ii * 8;
                g2lds16(QKV + (rowbase + kc * 128 + rb + r8) * 1536 + 512 + h * 64 + kg * 8,
                        &Ks[rb * 64]);
            }
        }
        {
            int v4 = lane >> 4;
            #pragma unroll
            for (int ii = 0; ii < 4; ii++) {
                int vb = w * 16 + ii * 4;
                int vd = vb + v4;
                int kg = (lane & 15) ^ (vd & 15);
                g2lds16(Vt + (size_t)bh * 32768 + (size_t)vd * 512 + kc * 128 + kg * 8,
                        &Vts[vb * 128]);
            }
        }
        float maskv[8];
        #pragma unroll
        for (int j = 0; j < 8; j++)
            maskv[j] = (tok[b * 512 + kc * 128 + j * 16 + l16] == 0) ? -1e9f : 0.f;

        __syncthreads();

        f32x4 sacc[2][8];
        #pragma unroll
        for (int i = 0; i < 2; i++)
            #pragma unroll
            for (int j = 0; j < 8; j++)
                sacc[i][j] = (f32x4){0.f, 0.f, 0.f, 0.f};
        #pragma unroll
        for (int tt = 0; tt < 2; tt++) {
            bf16x8 aq[2], bk8[8];
            #pragma unroll
            for (int i = 0; i < 2; i++) {
                int row = wm + i * 16 + l16;
                aq[i] = *(const bf16x8*)&Qs[row * 64 + (((tt << 2) + quad) ^ (row & 7)) * 8];
            }
            #pragma unroll
            for (int j = 0; j < 8; j++) {
                int row = j * 16 + l16;
                bk8[j] = *(const bf16x8*)&Ks[row * 64 + (((tt << 2) + quad) ^ (row & 7)) * 8];
            }
            #pragma unroll
            for (int i = 0; i < 2; i++)
                #pragma unroll
                for (int j = 0; j < 8; j++)
                    sacc[i][j] = __builtin_amdgcn_mfma_f32_16x16x32_bf16(
                        aq[i], bk8[j], sacc[i][j], 0, 0, 0);
        }

        #pragma unroll
        for (int i = 0; i < 2; i++)
            #pragma unroll
            for (int j = 0; j < 8; j++)
                #pragma unroll
                for (int r = 0; r < 4; r++) {
                    float p = __expf(fmaf(sacc[i][j][r], SCALE_QK, maskv[j]));
                    sacc[i][j][r] = p;
                    lrow[i][r] += p;
                }

        __syncthreads();                        // all QK reads of Ks(=Ps) done

        #pragma unroll
        for (int i = 0; i < 2; i++)
            #pragma unroll
            for (int j = 0; j < 8; j++) {
                int col = j * 16 + l16;
                int colc = col >> 3, csub = col & 7;
                #pragma unroll
                for (int r = 0; r < 4; r++) {
                    int row = wm + i * 16 + quad * 4 + r;
                    Ps[row * 128 + ((colc ^ (row & 15)) << 3) + csub] = f2bs(sacc[i][j][r]);
                }
            }

        #pragma unroll
        for (int tt = 0; tt < 4; tt++) {
            bf16x8 ap[2], bv8[4];
            #pragma unroll
            for (int i = 0; i < 2; i++) {
                int row = wm + i * 16 + l16;
                ap[i] = *(const bf16x8*)&Ps[row * 128 + ((((tt << 2) + quad)) ^ (row & 15)) * 8];
            }
            #pragma unroll
            for (int jv = 0; jv < 4; jv++) {
                int vd = jv * 16 + l16;
                bv8[jv] = *(const bf16x8*)&Vts[vd * 128 + (((tt << 2) + quad) ^ (vd & 15)) * 8];
            }
            #pragma unroll
            for (int i = 0; i < 2; i++)
                #pragma unroll
                for (int jv = 0; jv < 4; jv++)
                    accO[i][jv] = __builtin_amdgcn_mfma_f32_16x16x32_bf16(
                        ap[i], bv8[jv], accO[i][jv], 0, 0, 0);
        }
    }

    #pragma unroll
    for (int i = 0; i < 2; i++)
        #pragma unroll
        for (int r = 0; r < 4; r++) {
            float s = lrow[i][r];
            #pragma unroll
            for (int off = 1; off < 16; off <<= 1)
                s += __shfl_xor(s, off);
            float inv = 1.f / s;
            int row = q0 + wm + i * 16 + quad * 4 + r;
            #pragma unroll
            for (int jv = 0; jv < 4; jv++) {
                int vd = jv * 16 + l16;
                QKV[(rowbase + row) * 1536 + h * 64 + vd] = f2bs(accO[i][jv][r] * inv);
            }
        }
}

// ---------------------------------------------------------------------------
// prep: all weight transposes (f32 -> bf16, [R][C] -> [C][R]) + concat_bias
// + Fb zero + embed+PE in ONE dispatch (blockIdx ranges).
__global__ __launch_bounds__(256) void prep(
    const float* __restrict__ Wq, const float* __restrict__ Wk,
    const float* __restrict__ Wv, const float* __restrict__ Wo,
    const float* __restrict__ W1, const float* __restrict__ W2,
    const float* __restrict__ bq, const float* __restrict__ bk,
    const float* __restrict__ bv, const int* __restrict__ tok,
    const float* __restrict__ emb,
    __hip_bfloat16* __restrict__ WqkvT, __hip_bfloat16* __restrict__ WoT,
    __hip_bfloat16* __restrict__ W1T, __hip_bfloat16* __restrict__ W2T,
    float* __restrict__ bqkv, float* __restrict__ Fb,
    __hip_bfloat16* __restrict__ xb)
{
    const int blk = blockIdx.x;
    const int t = threadIdx.x;

    if (blk < 12288) {                          // ---- weight transposes ----
        __shared__ float tile[32][33];
        const float* in; __hip_bfloat16* out;
        long long inz, outz; int R, Cc, bx, by, bz;
        if (blk < 4096) {                       // Wq/Wk/Wv/Wo: 512x512, 16x16x4
            int seg = blk >> 10, lb = blk & 1023;
            bz = lb >> 8; by = (lb >> 4) & 15; bx = lb & 15;
            R = 512; Cc = 512; inz = 262144;
            if      (seg == 0) { in = Wq; out = WqkvT;          outz = 786432; }
            else if (seg == 1) { in = Wk; out = WqkvT + 262144; outz = 786432; }
            else if (seg == 2) { in = Wv; out = WqkvT + 524288; outz = 786432; }
            else               { in = Wo; out = WoT;            outz = 262144; }
        } else if (blk < 8192) {                // W1: 512x2048, 64x16x4
            int lb = blk - 4096;
            bz = lb >> 10; by = (lb >> 6) & 15; bx = lb & 63;
            R = 512; Cc = 2048; inz = 1048576; outz = 1048576;
            in = W1; out = W1T;
        } else {                                // W2: 2048x512, 16x64x4
            int lb = blk - 8192;
            bz = lb >> 10; by = (lb >> 4) & 63; bx = lb & 15;
            R = 2048; Cc = 512; inz = 1048576; outz = 1048576;
            in = W2; out = W2T;
        }
        in += bz * inz; out += bz * outz;
        int c0 = bx * 32, r0 = by * 32;
        int tx = t & 31, ty = t >> 5;
        #pragma unroll
        for (int i = 0; i < 4; i++)
            tile[ty + i * 8][tx] = in[(size_t)(r0 + ty + i * 8) * Cc + c0 + tx];
        __syncthreads();
        #pragma unroll
        for (int i = 0; i < 4; i++)
            out[(size_t)(c0 + ty + i * 8) * R + r0 + tx] =
                __float2bfloat16(tile[tx][ty + i * 8]);
    } else if (blk < 12312) {                   // ---- concat_bias + Fb=0 ----
        int k = blk - 12288;
        int idx = k * 256 + t;                  // < 6144 = 4*1536
        int l = idx / 1536, n = idx - l * 1536;
        float v = (n < 512) ? bq[l * 512 + n]
                : (n < 1024) ? bk[l * 512 + n - 512]
                             : bv[l * 512 + n - 1024];
        bqkv[idx] = v;
        if (k < 8) Fb[k * 256 + t] = 0.f;
    } else {                                    // ---- embed + PE ----
        int idx = (blk - 12312) * 256 + t;
        int d  = idx & 511;
        int bs = idx >> 9;
        int s  = bs & 511;
        int tk = tok[bs];
        float freq  = expf(-(float)(d & ~1) * PE_C);
        float angle = (float)s * freq;
        float pe    = (d & 1) ? cosf(angle) : sinf(angle);
        xb[idx] = __float2bfloat16(emb[(size_t)tk * 512 + d] + pe);
    }
}

// ---------------------------------------------------------------------------
// head stage 1 v3: 1024 blocks x 256 k-rows. NO global atomic chains.
__global__ __launch_bounds__(256) void feat_partial(const ushort_t* __restrict__ Xb,
                                                    const float* __restrict__ Wf,
                                                    float* __restrict__ FbP) {
    const int slice = blockIdx.x;           // 0..1023
    const int k0 = slice * 256;
    __shared__ float Xs[16][256];           // 16 KB
    __shared__ float RedW[4][16][128];      // 32 KB: per-wave partials
    const int t = threadIdx.x;

    #pragma unroll
    for (int i = 0; i < 4; i++) {           // 16 b x 256 k bf16 = 1024 ushort4
        int idx = t + i * 256;
        int b = idx >> 6, c4 = (idx & 63) * 4;
        ushort4 u = *(const ushort4*)&Xb[(size_t)b * 262144 + k0 + c4];
        Xs[b][c4 + 0] = bs2f(u.x);
        Xs[b][c4 + 1] = bs2f(u.y);
        Xs[b][c4 + 2] = bs2f(u.z);
        Xs[b][c4 + 3] = bs2f(u.w);
    }
    __syncthreads();

    const int n4 = (t & 31) * 4;
    const int kh = t >> 5;                  // 8 groups x 32 rows
    const int rbase = kh * 32;
    const int wv = t >> 6;                  // wave id (covers kh 2w, 2w+1)
    const float* wp = Wf + (size_t)(k0 + rbase) * 128 + n4;

    float4 acc[16];
    #pragma unroll
    for (int b = 0; b < 16; b++) acc[b] = (float4){0.f, 0.f, 0.f, 0.f};

    #pragma unroll
    for (int q = 0; q < 4; q++) {           // 4 batches of 8 rows in flight
        float4 wvv[8];
        #pragma unroll
        for (int kk = 0; kk < 8; kk++)
            wvv[kk] = *(const float4*)&wp[(size_t)(q * 8 + kk) * 128];
        #pragma unroll
        for (int b = 0; b < 16; b++) {
            float4 x0 = *(const float4*)&Xs[b][rbase + q * 8];
            float4 x1 = *(const float4*)&Xs[b][rbase + q * 8 + 4];
            acc[b].x += x0.x*wvv[0].x + x0.y*wvv[1].x + x0.z*wvv[2].x + x0.w*wvv[3].x
                      + x1.x*wvv[4].x + x1.y*wvv[5].x + x1.z*wvv[6].x + x1.w*wvv[7].x;
            acc[b].y += x0.x*wvv[0].y + x0.y*wvv[1].y + x0.z*wvv[2].y + x0.w*wvv[3].y
                      + x1.x*wvv[4].y + x1.y*wvv[5].y + x1.z*wvv[6].y + x1.w*wvv[7].y;
            acc[b].z += x0.x*wvv[0].z + x0.y*wvv[1].z + x0.z*wvv[2].z + x0.w*wvv[3].z
                      + x1.x*wvv[4].z + x1.y*wvv[5].z + x1.z*wvv[6].z + x1.w*wvv[7].z;
            acc[b].w += x0.x*wvv[0].w + x0.y*wvv[1].w + x0.z*wvv[2].w + x0.w*wvv[3].w
                      + x1.x*wvv[4].w + x1.y*wvv[5].w + x1.z*wvv[6].w + x1.w*wvv[7].w;
        }
    }

    // fold kh pair within wave (lane L and L+32 share n4)
    #pragma unroll
    for (int b = 0; b < 16; b++) {
        acc[b].x += __shfl_xor(acc[b].x, 32);
        acc[b].y += __shfl_xor(acc[b].y, 32);
        acc[b].z += __shfl_xor(acc[b].z, 32);
        acc[b].w += __shfl_xor(acc[b].w, 32);
    }
    if ((t & 63) < 32) {
        #pragma unroll
        for (int b = 0; b < 16; b++)
            *(float4*)&RedW[wv][b][n4] = acc[b];
    }
    __syncthreads();

    #pragma unroll
    for (int i = 0; i < 8; i++) {           // sum 4 wave-partials, store row
        int o = t + i * 256;
        int b = o >> 7, c = o & 127;
        FbP[(size_t)slice * 2048 + o] =
            RedW[0][b][c] + RedW[1][b][c] + RedW[2][b][c] + RedW[3][b][c];
    }
}

// feat_reduce: sum FbP[1024][2048] -> Fb[2048]. Atomic depth 16 per address.
__global__ __launch_bounds__(256) void feat_reduce(const float* __restrict__ FbP,
                                                   float* __restrict__ Fb) {
    int o = blockIdx.x * 256 + threadIdx.x;
    int g0 = blockIdx.y * 64;
    float s = 0.f;
    #pragma unroll
    for (int jj = 0; jj < 64; jj += 8) {
        float v[8];
        #pragma unroll
        for (int u = 0; u < 8; u++)
            v[u] = FbP[(size_t)(g0 + jj + u) * 2048 + o];
        #pragma unroll
        for (int u = 0; u < 8; u++) s += v[u];
    }
    atomicAdd(&Fb[o], s);
}

// out: [0..15]=y_score, [16..31]=y_pred, [32..2079]=features
__global__ __launch_bounds__(256) void head_kernel(const float* __restrict__ feat,
                                                   const float* __restrict__ bfv,
                                                   const float* __restrict__ Wo2,
                                                   const float* __restrict__ bo2,
                                                   float* __restrict__ out) {
    __shared__ float f[2048];
    int t = threadIdx.x;
    for (int i = t; i < 2048; i += 256) {
        float v = feat[i] + bfv[i & 127];
        f[i] = v;
        out[32 + i] = v;
    }
    __syncthreads();
    if (t < 16) {
        float zv = bo2[0];
        for (int n = 0; n < 128; n++) zv = fmaf(f[t * 128 + n], Wo2[n], zv);
        float ys = 1.f / (1.f + expf(-zv));
        out[t] = ys;
        out[16 + t] = rintf(ys);
    }
}

// ---------------------------------------------------------------------------
extern "C" void kernel_launch(void* const* d_in, const int* in_sizes, int n_in,
                              void* d_out, int out_size, void* d_ws, size_t ws_size,
                              hipStream_t stream) {
    const int*   enc  = (const int*)  d_in[0];
    const float* emb  = (const float*)d_in[1];
    const float* Wq   = (const float*)d_in[2];
    const float* bq   = (const float*)d_in[3];
    const float* Wk   = (const float*)d_in[4];
    const float* bk   = (const float*)d_in[5];
    const float* Wv   = (const float*)d_in[6];
    const float* bv   = (const float*)d_in[7];
    const float* Wo   = (const float*)d_in[8];
    const float* bo   = (const float*)d_in[9];
    const float* g1   = (const float*)d_in[10];
    const float* be1  = (const float*)d_in[11];
    const float* W1   = (const float*)d_in[12];
    const float* b1f  = (const float*)d_in[13];
    const float* W2   = (const float*)d_in[14];
    const float* b2f  = (const float*)d_in[15];
    const float* g2   = (const float*)d_in[16];
    const float* be2  = (const float*)d_in[17];
    const float* Wf   = (const float*)d_in[18];
    const float* bf   = (const float*)d_in[19];
    const float* Wout = (const float*)d_in[20];
    const float* bout = (const float*)d_in[21];
    float* out = (float*)d_out;

    // ---- workspace layout (bytes), peak < 119 MB ----
    char* ws = (char*)d_ws;
    ushort_t* Cpre = (ushort_t*) (ws + 0);           // [8192,512] bf16 (layers)
    float*    FbP  = (float*)    (ws + 0);           // [1024][2048] f32 (tail; aliases Cpre)
    ushort_t* Xb   = (ushort_t*) (ws + 16777216);    // [8192,512] bf16 activations
    ushort_t* QKV  = (ushort_t*) (ws + 25165824);    // [8192,1536] bf16
    ushort_t* Vt   = (ushort_t*) (ws + 50331648);    // [128][64][512] bf16
    ushort_t* S    = (ushort_t*) (ws + 58720256);    // FFN hidden [8192][2048] bf16
    ushort_t* WqkvT= (ushort_t*) (ws + 92274688);    // [4][1536][512] bf16
    ushort_t* WoT  = (ushort_t*) (ws + 98566144);    // [4][512][512] bf16
    ushort_t* W1T  = (ushort_t*) (ws + 100663296);   // [4][2048][512] bf16
    ushort_t* W2T  = (ushort_t*) (ws + 109051904);   // [4][512][2048] bf16
    float*    bqkv = (float*)    (ws + 117440512);   // [4][1536]
    float*    Fb   = (float*)    (ws + 117465088);   // [16][128]
    float2*   part = (float2*)   (ws + 117473280);   // [8192][8] LN stat partials

    typedef __hip_bfloat16 bf16;

    // one dispatch: 12288 transpose blocks + 24 concat blocks + 16384 embed
    prep<<<28696, 256, 0, stream>>>(
        Wq, Wk, Wv, Wo, W1, W2, bq, bk, bv, enc, emb,
        (bf16*)WqkvT, (bf16*)WoT, (bf16*)W1T, (bf16*)W2T, bqkv, Fb, (bf16*)Xb);

    for (int l = 0; l < 4; l++) {
        // QKV: [8192,512]x[512,1536]; V columns go transposed straight to Vt
        gemm8<false, true><<<dim3(6, 32), 512, 0, stream>>>(
            Xb, WqkvT + (size_t)l * 786432, bqkv + l * 1536,
            QKV, Vt, 512, 512, 512, 1536);

        flash_attn<<<dim3(4, 128), 256, 0, stream>>>(QKV, Vt, enc);

        // Wo: ctx @ WoT + bo + Xb -> Cpre bf16 + LN stat partials
        gemm4<<<dim3(4, 64), 256, 0, stream>>>(
            QKV, WoT + (size_t)l * 262144, bo + l * 512, Xb,
            Cpre, part, 512, 1536, 512, 512);
        ln_stats<<<8192, 256, 0, stream>>>(Cpre, part, g1 + l * 512, be1 + l * 512, Xb);

        // FFN1: relu(Xb @ W1T + b1) -> S bf16
        gemm8<true, false><<<dim3(8, 32), 512, 0, stream>>>(
            Xb, W1T + (size_t)l * 1048576, b1f + l * 2048,
            S, nullptr, 512, 512, 512, 2048);

        // FFN2: S @ W2T + b2 + Xb -> Cpre bf16 + LN stat partials
        gemm4<<<dim3(4, 64), 256, 0, stream>>>(
            S, W2T + (size_t)l * 1048576, b2f + l * 512, Xb,
            Cpre, part, 2048, 2048, 2048, 512);
        ln_stats<<<8192, 256, 0, stream>>>(Cpre, part, g2 + l * 512, be2 + l * 512, Xb);
    }

    feat_partial<<<1024, 256, 0, stream>>>(Xb, Wf, FbP);
    feat_reduce<<<dim3(8, 16), 256, 0, stream>>>(FbP, Fb);
    head_kernel<<<1, 256, 0, stream>>>(Fb, bf, Wout, bout, out);
}

// Round 6
// 894.859 us; speedup vs baseline: 1.0739x; 1.0739x over previous
//
#include <hip/hip_runtime.h>
#include <hip/hip_bf16.h>
#include <math.h>

typedef unsigned short ushort_t;
typedef __attribute__((ext_vector_type(8))) short bf16x8;   // 8 bf16 = 4 VGPRs
typedef __attribute__((ext_vector_type(4))) float f32x4;

#define SCALE_QK 0.04419417382415922f   // 1/sqrt(512)
#define PE_C 0.017988946039015986f      // ln(10000)/512

// ---------------------------------------------------------------------------
__device__ __forceinline__ void g2lds16(const void* g, void* l) {
    __builtin_amdgcn_global_load_lds(
        (const __attribute__((address_space(1))) unsigned int*)g,
        (__attribute__((address_space(3))) unsigned int*)l,
        16, 0, 0);
}
__device__ __forceinline__ ushort_t f2bs(float v) {
    __hip_bfloat16 h = __float2bfloat16(v);
    return *reinterpret_cast<ushort_t*>(&h);
}
__device__ __forceinline__ float bs2f(ushort_t v) {
    return __uint_as_float(((unsigned int)v) << 16);
}

// ---------------------------------------------------------------------------
// 256x256 / 8-wave GEMM with counted-vmcnt cross-barrier pipeline.
// Wave-tile 128x64 (MI=8,NJ=4). LDS double-buffer 128 KiB; loads for tile
// kt+2 issued after a RAW barrier and waited with vmcnt(8) -- 8 loads stay
// in flight across every barrier (never drain to 0 mid-loop).
// VT also folds SCALE_QK into the Q columns (n<512) so flash's exp arg is
// a plain add (score*scale pre-applied to Q; exact: (q+bq)*s dot k).
template<bool RELU, bool VT>
__global__ __launch_bounds__(512, 2) void gemm8(
    const ushort_t* __restrict__ A, const ushort_t* __restrict__ B,
    const float* __restrict__ bias, ushort_t* __restrict__ C,
    ushort_t* __restrict__ vt, int K, int lda, int ldb, int ldc)
{
    __shared__ ushort_t As[2][256 * 64];
    __shared__ ushort_t Bs[2][256 * 64];

    const int t = threadIdx.x;
    const int lane = t & 63, w = t >> 6;        // 8 waves
    const int l16 = lane & 15, quad = lane >> 4;
    const int r8 = lane >> 3;
    const int kg = ((lane & 7) ^ r8) << 3;      // swizzled global k-chunk
    const int wm = (w >> 2) * 128;              // 2 wave-rows (M)
    const int wn = (w & 3) * 64;                // 4 wave-cols (N)
    const int m0 = blockIdx.y * 256, n0 = blockIdx.x * 256;
    const int NT = K >> 6;

    f32x4 acc[8][4];
    #pragma unroll
    for (int i = 0; i < 8; i++)
        #pragma unroll
        for (int j = 0; j < 4; j++)
            acc[i][j] = (f32x4){0.f, 0.f, 0.f, 0.f};

    auto STAGE8 = [&](int kt, int bb) {
        int k0 = kt << 6;
        #pragma unroll
        for (int ii = 0; ii < 4; ii++) {        // 8 waves x 32 rows = 256
            int rbase = w * 32 + ii * 8;
            g2lds16(A + (size_t)(m0 + rbase + r8) * lda + k0 + kg,
                    &As[bb][rbase * 64]);
            g2lds16(B + (size_t)(n0 + rbase + r8) * ldb + k0 + kg,
                    &Bs[bb][rbase * 64]);
        }
    };

    STAGE8(0, 0);
    STAGE8(1, 1);

    for (int kt = 0; kt < NT; kt++) {
        const int bb = kt & 1;
        if (kt < NT - 1)
            asm volatile("s_waitcnt vmcnt(8)" ::: "memory");
        else
            asm volatile("s_waitcnt vmcnt(0)" ::: "memory");
        __builtin_amdgcn_s_barrier();           // all waves confirmed tile kt
        asm volatile("" ::: "memory");

        #pragma unroll
        for (int tt = 0; tt < 2; tt++) {
            bf16x8 af[8], bf[4];
            #pragma unroll
            for (int i = 0; i < 8; i++) {
                int row = wm + i * 16 + l16;
                af[i] = *(const bf16x8*)&As[bb][row * 64 + ((((tt << 2) + quad) ^ (row & 7)) << 3)];
            }
            #pragma unroll
            for (int j = 0; j < 4; j++) {
                int row = wn + j * 16 + l16;
                bf[j] = *(const bf16x8*)&Bs[bb][row * 64 + ((((tt << 2) + quad) ^ (row & 7)) << 3)];
            }
            #pragma unroll
            for (int i = 0; i < 8; i++)
                #pragma unroll
                for (int j = 0; j < 4; j++)
                    acc[i][j] = __builtin_amdgcn_mfma_f32_16x16x32_bf16(
                        af[i], bf[j], acc[i][j], 0, 0, 0);
        }

        asm volatile("" ::: "memory");
        __builtin_amdgcn_s_barrier();
        asm volatile("" ::: "memory");
        if (kt + 2 < NT)
            STAGE8(kt + 2, bb);
    }

    // ---- epilogue ----
    if (VT && n0 >= 1024) {
        #pragma unroll
        for (int i = 0; i < 8; i++) {
            int mbase = m0 + wm + i * 16 + quad * 4;
            int b = mbase >> 9, s = mbase & 511;
            #pragma unroll
            for (int j = 0; j < 4; j++) {
                int n = n0 + wn + j * 16 + l16;
                int hv = n - 1024;
                int h = hv >> 6, vd = hv & 63;
                float bv = bias[n];
                ushort4 pk;
                pk.x = f2bs(acc[i][j][0] + bv);
                pk.y = f2bs(acc[i][j][1] + bv);
                pk.z = f2bs(acc[i][j][2] + bv);
                pk.w = f2bs(acc[i][j][3] + bv);
                *(ushort4*)&vt[((size_t)((b << 3) + h)) * 32768 + (size_t)vd * 512 + s] = pk;
            }
        }
        return;
    }

    #pragma unroll
    for (int i = 0; i < 8; i++)
        #pragma unroll
        for (int j = 0; j < 4; j++) {
            int n = n0 + wn + j * 16 + l16;
            float bv = bias[n];
            #pragma unroll
            for (int r = 0; r < 4; r++) {
                int m = m0 + wm + i * 16 + quad * 4 + r;
                float v = acc[i][j][r] + bv;
                if (RELU) v = fmaxf(v, 0.f);
                if (VT && n < 512) v *= SCALE_QK;   // pre-scale Q for attn
                C[(size_t)m * ldc + n] = f2bs(v);
            }
        }
}

// ---------------------------------------------------------------------------
// Full-row GEMM + bias + residual + LayerNorm fused. BM=32, BN=512; grid =
// M/32 = 256 blocks = 1/CU. 8 waves (512 thr), wave-tile 32x64 -> 2
// waves/SIMD. Counted-vmcnt pipeline; staging: every wave 8 B-rows; waves
// 0-3 also 8 A-rows (+1) -> wave-uniform vmcnt(9)/vmcnt(8).
// A:[m][k] lda; B:[n][k] ldb=K; res/X: [m][512] bf16 (in-place safe).
__global__ __launch_bounds__(512) void gemmLN(
    const ushort_t* __restrict__ A, const ushort_t* __restrict__ B,
    const float* __restrict__ bias, const ushort_t* __restrict__ res,
    const float* __restrict__ g, const float* __restrict__ bt,
    ushort_t* __restrict__ X, int K, int lda)
{
    __shared__ ushort_t As[2][32 * 64];
    __shared__ ushort_t Bs[2][512 * 64];
    __shared__ float2 pst[8][32];
    __shared__ float2 rmv[32];

    const int t = threadIdx.x;
    const int lane = t & 63, w = t >> 6;        // 8 waves
    const int l16 = lane & 15, quad = lane >> 4;
    const int r8 = lane >> 3;
    const int kg = ((lane & 7) ^ r8) << 3;
    const int wn = w * 64;
    const int m0 = blockIdx.x * 32;
    const int NT = K >> 6;

    f32x4 acc[2][4];
    #pragma unroll
    for (int i = 0; i < 2; i++)
        #pragma unroll
        for (int j = 0; j < 4; j++)
            acc[i][j] = (f32x4){0.f, 0.f, 0.f, 0.f};

    auto STAGE = [&](int kt, int bb) {
        int k0 = kt << 6;
        if (w < 4)
            g2lds16(A + (size_t)(m0 + w * 8 + r8) * lda + k0 + kg,
                    &As[bb][(w * 8) * 64]);
        #pragma unroll
        for (int ii = 0; ii < 8; ii++) {
            int rbase = w * 64 + ii * 8;
            g2lds16(B + (size_t)(rbase + r8) * K + k0 + kg,
                    &Bs[bb][rbase * 64]);
        }
    };

    STAGE(0, 0);
    STAGE(1, 1);

    for (int kt = 0; kt < NT; kt++) {
        const int bb = kt & 1;
        if (kt < NT - 1) {
            if (w < 4) asm volatile("s_waitcnt vmcnt(9)" ::: "memory");
            else       asm volatile("s_waitcnt vmcnt(8)" ::: "memory");
        } else {
            asm volatile("s_waitcnt vmcnt(0)" ::: "memory");
        }
        __builtin_amdgcn_s_barrier();
        asm volatile("" ::: "memory");

        #pragma unroll
        for (int tt = 0; tt < 2; tt++) {
            bf16x8 af[2], bf4[4];
            #pragma unroll
            for (int i = 0; i < 2; i++) {
                int row = i * 16 + l16;
                af[i] = *(const bf16x8*)&As[bb][row * 64 + ((((tt << 2) + quad) ^ (row & 7)) << 3)];
            }
            #pragma unroll
            for (int j = 0; j < 4; j++) {
                int row = wn + j * 16 + l16;
                bf4[j] = *(const bf16x8*)&Bs[bb][row * 64 + ((((tt << 2) + quad) ^ (row & 7)) << 3)];
            }
            #pragma unroll
            for (int i = 0; i < 2; i++)
                #pragma unroll
                for (int j = 0; j < 4; j++)
                    acc[i][j] = __builtin_amdgcn_mfma_f32_16x16x32_bf16(
                        af[i], bf4[j], acc[i][j], 0, 0, 0);
        }

        asm volatile("" ::: "memory");
        __builtin_amdgcn_s_barrier();
        asm volatile("" ::: "memory");
        if (kt + 2 < NT)
            STAGE(kt + 2, bb);
    }

    // ---- epilogue: v = acc + bias + residual; LN over full 512-row ----
    float rs[2][4], rq[2][4];
    #pragma unroll
    for (int i = 0; i < 2; i++)
        #pragma unroll
        for (int r = 0; r < 4; r++) { rs[i][r] = 0.f; rq[i][r] = 0.f; }

    #pragma unroll
    for (int i = 0; i < 2; i++)
        #pragma unroll
        for (int j = 0; j < 4; j++) {
            int n = wn + j * 16 + l16;
            float bvn = bias[n];
            #pragma unroll
            for (int r = 0; r < 4; r++) {
                int row = i * 16 + quad * 4 + r;
                float v = acc[i][j][r] + bvn
                        + bs2f(res[(size_t)(m0 + row) * 512 + n]);
                acc[i][j][r] = v;
                rs[i][r] += v;
                rq[i][r] += v * v;
            }
        }

    #pragma unroll
    for (int i = 0; i < 2; i++)
        #pragma unroll
        for (int r = 0; r < 4; r++) {
            #pragma unroll
            for (int off = 1; off < 16; off <<= 1) {
                rs[i][r] += __shfl_xor(rs[i][r], off);
                rq[i][r] += __shfl_xor(rq[i][r], off);
            }
            if (l16 == 0)
                pst[w][i * 16 + quad * 4 + r] = make_float2(rs[i][r], rq[i][r]);
        }
    __syncthreads();
    if (t < 32) {
        float s = 0.f, q = 0.f;
        #pragma unroll
        for (int wv = 0; wv < 8; wv++) {
            float2 p = pst[wv][t];
            s += p.x; q += p.y;
        }
        float mean = s * (1.f / 512.f);
        float var = q * (1.f / 512.f) - mean * mean;
        rmv[t] = make_float2(mean, rsqrtf(var + 1e-5f));
    }
    __syncthreads();

    #pragma unroll
    for (int i = 0; i < 2; i++)
        #pragma unroll
        for (int j = 0; j < 4; j++) {
            int n = wn + j * 16 + l16;
            float gn = g[n], btn = bt[n];
            #pragma unroll
            for (int r = 0; r < 4; r++) {
                int row = i * 16 + quad * 4 + r;
                float2 mr = rmv[row];
                float o = (acc[i][j][r] - mr.x) * mr.y * gn + btn;
                X[(size_t)(m0 + row) * 512 + n] = f2bs(o);
            }
        }
}

// ---------------------------------------------------------------------------
// Fused flash attention (R4 version: 80 KB LDS, 2 blocks/CU, 2 barriers/kc).
// Q pre-scaled by 1/sqrt(512) in the QKV GEMM -> exp arg is a plain add.
__global__ __launch_bounds__(256) void flash_attn(
    ushort_t* __restrict__ QKV, const ushort_t* __restrict__ Vt,
    const int* __restrict__ tok)
{
    __shared__ ushort_t Qs[128 * 64];
    __shared__ ushort_t Ks[128 * 64];
    __shared__ ushort_t Vts[64 * 128];
    __shared__ ushort_t Ps[128 * 128];

    const int bh = blockIdx.y;
    const int b = bh >> 3, h = bh & 7;
    const int q0 = blockIdx.x * 128;
    const int t = threadIdx.x;
    const int lane = t & 63, w = t >> 6;
    const int l16 = lane & 15, quad = lane >> 4;
    const int wm = w * 32;
    const size_t rowbase = (size_t)b * 512;

    {
        int r8 = lane >> 3;
        int kg = (lane & 7) ^ r8;
        #pragma unroll
        for (int ii = 0; ii < 4; ii++) {
            int rb = w * 32 + ii * 8;
            g2lds16(QKV + (rowbase + q0 + rb + r8) * 1536 + h * 64 + kg * 8,
                    &Qs[rb * 64]);
        }
    }

    f32x4 accO[2][4];
    #pragma unroll
    for (int i = 0; i < 2; i++)
        #pragma unroll
        for (int jv = 0; jv < 4; jv++)
            accO[i][jv] = (f32x4){0.f, 0.f, 0.f, 0.f};
    float lrow[2][4];
    #pragma unroll
    for (int i = 0; i < 2; i++)
        #pragma unroll
        for (int r = 0; r < 4; r++) lrow[i][r] = 0.f;

    for (int kc = 0; kc < 4; kc++) {
        __syncthreads();
        {
            int r8 = lane >> 3;
            int kg = (lane & 7) ^ r8;
            #pragma unroll
            for (int ii = 0; ii < 4; ii++) {
                int rb = w * 32 + ii * 8;
                g2lds16(QKV + (rowbase + kc * 128 + rb + r8) * 1536 + 512 + h * 64 + kg * 8,
                        &Ks[rb * 64]);
            }
        }
        {
            int v4 = lane >> 4;
            #pragma unroll
            for (int ii = 0; ii < 4; ii++) {
                int vb = w * 16 + ii * 4;
                int vd = vb + v4;
                int kg = (lane & 15) ^ (vd & 15);
                g2lds16(Vt + (size_t)bh * 32768 + (size_t)vd * 512 + kc * 128 + kg * 8,
                        &Vts[vb * 128]);
            }
        }
        float maskv[8];
        #pragma unroll
        for (int j = 0; j < 8; j++)
            maskv[j] = (tok[b * 512 + kc * 128 + j * 16 + l16] == 0) ? -1e9f : 0.f;

        __syncthreads();

        f32x4 sacc[2][8];
        #pragma unroll
        for (int i = 0; i < 2; i++)
            #pragma unroll
            for (int j = 0; j < 8; j++)
                sacc[i][j] = (f32x4){0.f, 0.f, 0.f, 0.f};
        #pragma unroll
        for (int tt = 0; tt < 2; tt++) {
            bf16x8 aq[2], bk8[8];
            #pragma unroll
            for (int i = 0; i < 2; i++) {
                int row = wm + i * 16 + l16;
                aq[i] = *(const bf16x8*)&Qs[row * 64 + (((tt << 2) + quad) ^ (row & 7)) * 8];
            }
            #pragma unroll
            for (int j = 0; j < 8; j++) {
                int row = j * 16 + l16;
                bk8[j] = *(const bf16x8*)&Ks[row * 64 + (((tt << 2) + quad) ^ (row & 7)) * 8];
            }
            #pragma unroll
            for (int i = 0; i < 2; i++)
                #pragma unroll
                for (int j = 0; j < 8; j++)
                    sacc[i][j] = __builtin_amdgcn_mfma_f32_16x16x32_bf16(
                        aq[i], bk8[j], sacc[i][j], 0, 0, 0);
        }

        #pragma unroll
        for (int i = 0; i < 2; i++)
            #pragma unroll
            for (int j = 0; j < 8; j++)
                #pragma unroll
                for (int r = 0; r < 4; r++) {
                    float p = __expf(sacc[i][j][r] + maskv[j]);
                    sacc[i][j][r] = p;
                    lrow[i][r] += p;
                }

        #pragma unroll
        for (int i = 0; i < 2; i++)
            #pragma unroll
            for (int j = 0; j < 8; j++) {
                int col = j * 16 + l16;
                int colc = col >> 3, csub = col & 7;
                #pragma unroll
                for (int r = 0; r < 4; r++) {
                    int row = wm + i * 16 + quad * 4 + r;
                    Ps[row * 128 + ((colc ^ (row & 15)) << 3) + csub] = f2bs(sacc[i][j][r]);
                }
            }

        #pragma unroll
        for (int tt = 0; tt < 4; tt++) {
            bf16x8 ap[2], bv8[4];
            #pragma unroll
            for (int i = 0; i < 2; i++) {
                int row = wm + i * 16 + l16;
                ap[i] = *(const bf16x8*)&Ps[row * 128 + ((((tt << 2) + quad)) ^ (row & 15)) * 8];
            }
            #pragma unroll
            for (int jv = 0; jv < 4; jv++) {
                int vd = jv * 16 + l16;
                bv8[jv] = *(const bf16x8*)&Vts[vd * 128 + (((tt << 2) + quad) ^ (vd & 15)) * 8];
            }
            #pragma unroll
            for (int i = 0; i < 2; i++)
                #pragma unroll
                for (int jv = 0; jv < 4; jv++)
                    accO[i][jv] = __builtin_amdgcn_mfma_f32_16x16x32_bf16(
                        ap[i], bv8[jv], accO[i][jv], 0, 0, 0);
        }
    }

    #pragma unroll
    for (int i = 0; i < 2; i++)
        #pragma unroll
        for (int r = 0; r < 4; r++) {
            float s = lrow[i][r];
            #pragma unroll
            for (int off = 1; off < 16; off <<= 1)
                s += __shfl_xor(s, off);
            float inv = 1.f / s;
            int row = q0 + wm + i * 16 + quad * 4 + r;
            #pragma unroll
            for (int jv = 0; jv < 4; jv++) {
                int vd = jv * 16 + l16;
                QKV[(rowbase + row) * 1536 + h * 64 + vd] = f2bs(accO[i][jv][r] * inv);
            }
        }
}

// ---------------------------------------------------------------------------
// prep: all weight transposes (f32 -> bf16, [R][C] -> [C][R]) + concat_bias
// + Fb zero + embed+PE in ONE dispatch (blockIdx ranges).
// embed restructured: one block per s (512 blocks); trig computed ONCE per
// (s,d) and reused across the 16 batches (was per (b,s,d): 16x fewer
// transcendentals). Tokens broadcast via LDS.
__global__ __launch_bounds__(256) void prep(
    const float* __restrict__ Wq, const float* __restrict__ Wk,
    const float* __restrict__ Wv, const float* __restrict__ Wo,
    const float* __restrict__ W1, const float* __restrict__ W2,
    const float* __restrict__ bq, const float* __restrict__ bk,
    const float* __restrict__ bv, const int* __restrict__ tok,
    const float* __restrict__ emb,
    __hip_bfloat16* __restrict__ WqkvT, __hip_bfloat16* __restrict__ WoT,
    __hip_bfloat16* __restrict__ W1T, __hip_bfloat16* __restrict__ W2T,
    float* __restrict__ bqkv, float* __restrict__ Fb,
    ushort_t* __restrict__ xb)
{
    const int blk = blockIdx.x;
    const int t = threadIdx.x;

    if (blk < 12288) {                          // ---- weight transposes ----
        __shared__ float tile[32][33];
        const float* in; __hip_bfloat16* out;
        long long inz, outz; int R, Cc, bx, by, bz;
        if (blk < 4096) {                       // Wq/Wk/Wv/Wo: 512x512, 16x16x4
            int seg = blk >> 10, lb = blk & 1023;
            bz = lb >> 8; by = (lb >> 4) & 15; bx = lb & 15;
            R = 512; Cc = 512; inz = 262144;
            if      (seg == 0) { in = Wq; out = WqkvT;          outz = 786432; }
            else if (seg == 1) { in = Wk; out = WqkvT + 262144; outz = 786432; }
            else if (seg == 2) { in = Wv; out = WqkvT + 524288; outz = 786432; }
            else               { in = Wo; out = WoT;            outz = 262144; }
        } else if (blk < 8192) {                // W1: 512x2048, 64x16x4
            int lb = blk - 4096;
            bz = lb >> 10; by = (lb >> 6) & 15; bx = lb & 63;
            R = 512; Cc = 2048; inz = 1048576; outz = 1048576;
            in = W1; out = W1T;
        } else {                                // W2: 2048x512, 16x64x4
            int lb = blk - 8192;
            bz = lb >> 10; by = (lb >> 4) & 63; bx = lb & 15;
            R = 2048; Cc = 512; inz = 1048576; outz = 1048576;
            in = W2; out = W2T;
        }
        in += bz * inz; out += bz * outz;
        int c0 = bx * 32, r0 = by * 32;
        int tx = t & 31, ty = t >> 5;
        #pragma unroll
        for (int i = 0; i < 4; i++)
            tile[ty + i * 8][tx] = in[(size_t)(r0 + ty + i * 8) * Cc + c0 + tx];
        __syncthreads();
        #pragma unroll
        for (int i = 0; i < 4; i++)
            out[(size_t)(c0 + ty + i * 8) * R + r0 + tx] =
                __float2bfloat16(tile[tx][ty + i * 8]);
    } else if (blk < 12312) {                   // ---- concat_bias + Fb=0 ----
        int k = blk - 12288;
        int idx = k * 256 + t;                  // < 6144 = 4*1536
        int l = idx / 1536, n = idx - l * 1536;
        float v = (n < 512) ? bq[l * 512 + n]
                : (n < 1024) ? bk[l * 512 + n - 512]
                             : bv[l * 512 + n - 1024];
        bqkv[idx] = v;
        if (k < 8) Fb[k * 256 + t] = 0.f;
    } else {                                    // ---- embed + PE: 1 block/s --
        int s = blk - 12312;                    // 0..511
        int d0 = t * 2;
        float freq = __expf(-(float)d0 * PE_C);
        float angle = (float)s * freq;
        float sv, cv;
        __sincosf(angle, &sv, &cv);
        __shared__ int toks[16];
        if (t < 16) toks[t] = tok[t * 512 + s];
        __syncthreads();
        #pragma unroll
        for (int b = 0; b < 16; b++) {
            int tk = toks[b];
            float2 e = *(const float2*)&emb[(size_t)tk * 512 + d0];
            ushort2 o;
            o.x = f2bs(e.x + sv);
            o.y = f2bs(e.y + cv);
            *(ushort2*)&xb[((size_t)(b * 512 + s)) * 512 + d0] = o;
        }
    }
}

// ---------------------------------------------------------------------------
// head stage 1 v3: 1024 blocks x 256 k-rows. NO global atomic chains.
__global__ __launch_bounds__(256) void feat_partial(const ushort_t* __restrict__ Xb,
                                                    const float* __restrict__ Wf,
                                                    float* __restrict__ FbP) {
    const int slice = blockIdx.x;           // 0..1023
    const int k0 = slice * 256;
    __shared__ float Xs[16][256];           // 16 KB
    __shared__ float RedW[4][16][128];      // 32 KB: per-wave partials
    const int t = threadIdx.x;

    #pragma unroll
    for (int i = 0; i < 4; i++) {           // 16 b x 256 k bf16 = 1024 ushort4
        int idx = t + i * 256;
        int b = idx >> 6, c4 = (idx & 63) * 4;
        ushort4 u = *(const ushort4*)&Xb[(size_t)b * 262144 + k0 + c4];
        Xs[b][c4 + 0] = bs2f(u.x);
        Xs[b][c4 + 1] = bs2f(u.y);
        Xs[b][c4 + 2] = bs2f(u.z);
        Xs[b][c4 + 3] = bs2f(u.w);
    }
    __syncthreads();

    const int n4 = (t & 31) * 4;
    const int kh = t >> 5;                  // 8 groups x 32 rows
    const int rbase = kh * 32;
    const int wv = t >> 6;                  // wave id (covers kh 2w, 2w+1)
    const float* wp = Wf + (size_t)(k0 + rbase) * 128 + n4;

    float4 acc[16];
    #pragma unroll
    for (int b = 0; b < 16; b++) acc[b] = (float4){0.f, 0.f, 0.f, 0.f};

    #pragma unroll
    for (int q = 0; q < 4; q++) {           // 4 batches of 8 rows in flight
        float4 wvv[8];
        #pragma unroll
        for (int kk = 0; kk < 8; kk++)
            wvv[kk] = *(const float4*)&wp[(size_t)(q * 8 + kk) * 128];
        #pragma unroll
        for (int b = 0; b < 16; b++) {
            float4 x0 = *(const float4*)&Xs[b][rbase + q * 8];
            float4 x1 = *(const float4*)&Xs[b][rbase + q * 8 + 4];
            acc[b].x += x0.x*wvv[0].x + x0.y*wvv[1].x + x0.z*wvv[2].x + x0.w*wvv[3].x
                      + x1.x*wvv[4].x + x1.y*wvv[5].x + x1.z*wvv[6].x + x1.w*wvv[7].x;
            acc[b].y += x0.x*wvv[0].y + x0.y*wvv[1].y + x0.z*wvv[2].y + x0.w*wvv[3].y
                      + x1.x*wvv[4].y + x1.y*wvv[5].y + x1.z*wvv[6].y + x1.w*wvv[7].y;
            acc[b].z += x0.x*wvv[0].z + x0.y*wvv[1].z + x0.z*wvv[2].z + x0.w*wvv[3].z
                      + x1.x*wvv[4].z + x1.y*wvv[5].z + x1.z*wvv[6].z + x1.w*wvv[7].z;
            acc[b].w += x0.x*wvv[0].w + x0.y*wvv[1].w + x0.z*wvv[2].w + x0.w*wvv[3].w
                      + x1.x*wvv[4].w + x1.y*wvv[5].w + x1.z*wvv[6].w + x1.w*wvv[7].w;
        }
    }

    // fold kh pair within wave (lane L and L+32 share n4)
    #pragma unroll
    for (int b = 0; b < 16; b++) {
        acc[b].x += __shfl_xor(acc[b].x, 32);
        acc[b].y += __shfl_xor(acc[b].y, 32);
        acc[b].z += __shfl_xor(acc[b].z, 32);
        acc[b].w += __shfl_xor(acc[b].w, 32);
    }
    if ((t & 63) < 32) {
        #pragma unroll
        for (int b = 0; b < 16; b++)
            *(float4*)&RedW[wv][b][n4] = acc[b];
    }
    __syncthreads();

    #pragma unroll
    for (int i = 0; i < 8; i++) {           // sum 4 wave-partials, store row
        int o = t + i * 256;
        int b = o >> 7, c = o & 127;
        FbP[(size_t)slice * 2048 + o] =
            RedW[0][b][c] + RedW[1][b][c] + RedW[2][b][c] + RedW[3][b][c];
    }
}

// feat_reduce: sum FbP[1024][2048] -> Fb[2048]. Atomic depth 16 per address.
__global__ __launch_bounds__(256) void feat_reduce(const float* __restrict__ FbP,
                                                   float* __restrict__ Fb) {
    int o = blockIdx.x * 256 + threadIdx.x;
    int g0 = blockIdx.y * 64;
    float s = 0.f;
    #pragma unroll
    for (int jj = 0; jj < 64; jj += 8) {
        float v[8];
        #pragma unroll
        for (int u = 0; u < 8; u++)
            v[u] = FbP[(size_t)(g0 + jj + u) * 2048 + o];
        #pragma unroll
        for (int u = 0; u < 8; u++) s += v[u];
    }
    atomicAdd(&Fb[o], s);
}

// out: [0..15]=y_score, [16..31]=y_pred, [32..2079]=features
__global__ __launch_bounds__(256) void head_kernel(const float* __restrict__ feat,
                                                   const float* __restrict__ bfv,
                                                   const float* __restrict__ Wo2,
                                                   const float* __restrict__ bo2,
                                                   float* __restrict__ out) {
    __shared__ float f[2048];
    int t = threadIdx.x;
    for (int i = t; i < 2048; i += 256) {
        float v = feat[i] + bfv[i & 127];
        f[i] = v;
        out[32 + i] = v;
    }
    __syncthreads();
    if (t < 16) {
        float zv = bo2[0];
        for (int n = 0; n < 128; n++) zv = fmaf(f[t * 128 + n], Wo2[n], zv);
        float ys = 1.f / (1.f + expf(-zv));
        out[t] = ys;
        out[16 + t] = rintf(ys);
    }
}

// ---------------------------------------------------------------------------
extern "C" void kernel_launch(void* const* d_in, const int* in_sizes, int n_in,
                              void* d_out, int out_size, void* d_ws, size_t ws_size,
                              hipStream_t stream) {
    const int*   enc  = (const int*)  d_in[0];
    const float* emb  = (const float*)d_in[1];
    const float* Wq   = (const float*)d_in[2];
    const float* bq   = (const float*)d_in[3];
    const float* Wk   = (const float*)d_in[4];
    const float* bk   = (const float*)d_in[5];
    const float* Wv   = (const float*)d_in[6];
    const float* bv   = (const float*)d_in[7];
    const float* Wo   = (const float*)d_in[8];
    const float* bo   = (const float*)d_in[9];
    const float* g1   = (const float*)d_in[10];
    const float* be1  = (const float*)d_in[11];
    const float* W1   = (const float*)d_in[12];
    const float* b1f  = (const float*)d_in[13];
    const float* W2   = (const float*)d_in[14];
    const float* b2f  = (const float*)d_in[15];
    const float* g2   = (const float*)d_in[16];
    const float* be2  = (const float*)d_in[17];
    const float* Wf   = (const float*)d_in[18];
    const float* bf   = (const float*)d_in[19];
    const float* Wout = (const float*)d_in[20];
    const float* bout = (const float*)d_in[21];
    float* out = (float*)d_out;

    // ---- workspace layout (bytes), peak < 119 MB ----
    char* ws = (char*)d_ws;
    float*    FbP  = (float*)    (ws + 0);           // [1024][2048] f32 (tail)
    ushort_t* Xb   = (ushort_t*) (ws + 16777216);    // [8192,512] bf16 activations
    ushort_t* QKV  = (ushort_t*) (ws + 25165824);    // [8192,1536] bf16
    ushort_t* Vt   = (ushort_t*) (ws + 50331648);    // [128][64][512] bf16
    ushort_t* S    = (ushort_t*) (ws + 58720256);    // FFN hidden [8192][2048] bf16
    ushort_t* WqkvT= (ushort_t*) (ws + 92274688);    // [4][1536][512] bf16
    ushort_t* WoT  = (ushort_t*) (ws + 98566144);    // [4][512][512] bf16
    ushort_t* W1T  = (ushort_t*) (ws + 100663296);   // [4][2048][512] bf16
    ushort_t* W2T  = (ushort_t*) (ws + 109051904);   // [4][512][2048] bf16
    float*    bqkv = (float*)    (ws + 117440512);   // [4][1536]
    float*    Fb   = (float*)    (ws + 117465088);   // [16][128]

    typedef __hip_bfloat16 bf16;

    // one dispatch: 12288 transpose + 24 concat + 512 embed (1 block per s)
    prep<<<12824, 256, 0, stream>>>(
        Wq, Wk, Wv, Wo, W1, W2, bq, bk, bv, enc, emb,
        (bf16*)WqkvT, (bf16*)WoT, (bf16*)W1T, (bf16*)W2T, bqkv, Fb, Xb);

    for (int l = 0; l < 4; l++) {
        // QKV: [8192,512]x[512,1536]; V columns go transposed straight to Vt;
        // Q columns pre-scaled by 1/sqrt(512)
        gemm8<false, true><<<dim3(6, 32), 512, 0, stream>>>(
            Xb, WqkvT + (size_t)l * 786432, bqkv + l * 1536,
            QKV, Vt, 512, 512, 512, 1536);

        flash_attn<<<dim3(4, 128), 256, 0, stream>>>(QKV, Vt, enc);

        // Wo + bo + residual + LN1 fused -> Xb
        gemmLN<<<256, 512, 0, stream>>>(
            QKV, WoT + (size_t)l * 262144, bo + l * 512, Xb,
            g1 + l * 512, be1 + l * 512, Xb, 512, 1536);

        // FFN1: relu(Xb @ W1T + b1) -> S bf16
        gemm8<true, false><<<dim3(8, 32), 512, 0, stream>>>(
            Xb, W1T + (size_t)l * 1048576, b1f + l * 2048,
            S, nullptr, 512, 512, 512, 2048);

        // FFN2 + b2 + residual + LN2 fused -> Xb
        gemmLN<<<256, 512, 0, stream>>>(
            S, W2T + (size_t)l * 1048576, b2f + l * 512, Xb,
            g2 + l * 512, be2 + l * 512, Xb, 2048, 2048);
    }

    feat_partial<<<1024, 256, 0, stream>>>(Xb, Wf, FbP);
    feat_reduce<<<dim3(8, 16), 256, 0, stream>>>(FbP, Fb);
    head_kernel<<<1, 256, 0, stream>>>(Fb, bf, Wout, bout, out);
}

// Round 7
// 889.136 us; speedup vs baseline: 1.0808x; 1.0064x over previous
//
#include <hip/hip_runtime.h>
#include <hip/hip_bf16.h>
#include <math.h>

typedef unsigned short ushort_t;
typedef __attribute__((ext_vector_type(8))) short bf16x8;   // 8 bf16 = 4 VGPRs
typedef __attribute__((ext_vector_type(4))) float f32x4;

#define SCALE_QK 0.04419417382415922f   // 1/sqrt(512)
#define PE_C 0.017988946039015986f      // ln(10000)/512

// ---------------------------------------------------------------------------
__device__ __forceinline__ void g2lds16(const void* g, void* l) {
    __builtin_amdgcn_global_load_lds(
        (const __attribute__((address_space(1))) unsigned int*)g,
        (__attribute__((address_space(3))) unsigned int*)l,
        16, 0, 0);
}
__device__ __forceinline__ ushort_t f2bs(float v) {
    __hip_bfloat16 h = __float2bfloat16(v);
    return *reinterpret_cast<ushort_t*>(&h);
}
__device__ __forceinline__ float bs2f(ushort_t v) {
    return __uint_as_float(((unsigned int)v) << 16);
}

// ---------------------------------------------------------------------------
// 128x128 / 4-wave GEMM, 64 KB LDS double-buffer -> 2 blocks/CU (the m114
// cross-block overlap hides each block's vmcnt/barrier stalls; gemm8's
// 128 KB variant capped at 1 block/CU and exposed them). Counted-vmcnt
// pipeline: loads for tile kt+2 issued after the trailing barrier, waited
// with vmcnt(8) (8 loads in flight across every barrier, never 0 mid-loop).
// Wave-tile 64x64 (MI=4,NJ=4). VT: blocks with n0>=1024 (QKV's V region)
// write transposed into vt[bh][vd][s]; VT also pre-scales Q cols (n<512) by
// 1/sqrt(512) so flash's exp arg is a plain add.
template<bool RELU, bool VT>
__global__ __launch_bounds__(256, 2) void gemm4t(
    const ushort_t* __restrict__ A, const ushort_t* __restrict__ B,
    const float* __restrict__ bias, ushort_t* __restrict__ C,
    ushort_t* __restrict__ vt, int K, int lda, int ldb, int ldc)
{
    __shared__ ushort_t As[2][128 * 64];
    __shared__ ushort_t Bs[2][128 * 64];

    const int t = threadIdx.x;
    const int lane = t & 63, w = t >> 6;        // 4 waves
    const int l16 = lane & 15, quad = lane >> 4;
    const int r8 = lane >> 3;
    const int kg = ((lane & 7) ^ r8) << 3;      // swizzled global k-chunk
    const int wm = (w >> 1) * 64;
    const int wn = (w & 1) * 64;
    const int m0 = blockIdx.y * 128, n0 = blockIdx.x * 128;
    const int NT = K >> 6;

    f32x4 acc[4][4];
    #pragma unroll
    for (int i = 0; i < 4; i++)
        #pragma unroll
        for (int j = 0; j < 4; j++)
            acc[i][j] = (f32x4){0.f, 0.f, 0.f, 0.f};

    auto STAGE = [&](int kt, int bb) {
        int k0 = kt << 6;
        #pragma unroll
        for (int ii = 0; ii < 4; ii++) {        // 4 waves x 32 rows = 128
            int rbase = w * 32 + ii * 8;
            g2lds16(A + (size_t)(m0 + rbase + r8) * lda + k0 + kg,
                    &As[bb][rbase * 64]);
            g2lds16(B + (size_t)(n0 + rbase + r8) * ldb + k0 + kg,
                    &Bs[bb][rbase * 64]);
        }
    };

    STAGE(0, 0);
    STAGE(1, 1);

    for (int kt = 0; kt < NT; kt++) {
        const int bb = kt & 1;
        if (kt < NT - 1)
            asm volatile("s_waitcnt vmcnt(8)" ::: "memory");
        else
            asm volatile("s_waitcnt vmcnt(0)" ::: "memory");
        __builtin_amdgcn_s_barrier();
        asm volatile("" ::: "memory");

        #pragma unroll
        for (int tt = 0; tt < 2; tt++) {
            bf16x8 af[4], bf[4];
            #pragma unroll
            for (int i = 0; i < 4; i++) {
                int row = wm + i * 16 + l16;
                af[i] = *(const bf16x8*)&As[bb][row * 64 + ((((tt << 2) + quad) ^ (row & 7)) << 3)];
            }
            #pragma unroll
            for (int j = 0; j < 4; j++) {
                int row = wn + j * 16 + l16;
                bf[j] = *(const bf16x8*)&Bs[bb][row * 64 + ((((tt << 2) + quad) ^ (row & 7)) << 3)];
            }
            #pragma unroll
            for (int i = 0; i < 4; i++)
                #pragma unroll
                for (int j = 0; j < 4; j++)
                    acc[i][j] = __builtin_amdgcn_mfma_f32_16x16x32_bf16(
                        af[i], bf[j], acc[i][j], 0, 0, 0);
        }

        asm volatile("" ::: "memory");
        __builtin_amdgcn_s_barrier();
        asm volatile("" ::: "memory");
        if (kt + 2 < NT)
            STAGE(kt + 2, bb);
    }

    // ---- epilogue ----
    if (VT && n0 >= 1024) {
        #pragma unroll
        for (int i = 0; i < 4; i++) {
            int mbase = m0 + wm + i * 16 + quad * 4;
            int b = mbase >> 9, s = mbase & 511;
            #pragma unroll
            for (int j = 0; j < 4; j++) {
                int n = n0 + wn + j * 16 + l16;
                int hv = n - 1024;
                int h = hv >> 6, vd = hv & 63;
                float bv = bias[n];
                ushort4 pk;
                pk.x = f2bs(acc[i][j][0] + bv);
                pk.y = f2bs(acc[i][j][1] + bv);
                pk.z = f2bs(acc[i][j][2] + bv);
                pk.w = f2bs(acc[i][j][3] + bv);
                *(ushort4*)&vt[((size_t)((b << 3) + h)) * 32768 + (size_t)vd * 512 + s] = pk;
            }
        }
        return;
    }

    #pragma unroll
    for (int i = 0; i < 4; i++)
        #pragma unroll
        for (int j = 0; j < 4; j++) {
            int n = n0 + wn + j * 16 + l16;
            float bv = bias[n];
            #pragma unroll
            for (int r = 0; r < 4; r++) {
                int m = m0 + wm + i * 16 + quad * 4 + r;
                float v = acc[i][j][r] + bv;
                if (RELU) v = fmaxf(v, 0.f);
                if (VT && n < 512) v *= SCALE_QK;   // pre-scale Q for attn
                C[(size_t)m * ldc + n] = f2bs(v);
            }
        }
}

// ---------------------------------------------------------------------------
// Full-row GEMM + bias + residual + LayerNorm fused. BM=32, BN=512; grid =
// M/32 = 256 blocks = 1/CU. 8 waves (512 thr), wave-tile 32x64 -> 2
// waves/SIMD. Counted-vmcnt pipeline; staging: every wave 8 B-rows; waves
// 0-3 also 8 A-rows (+1) -> wave-uniform vmcnt(9)/vmcnt(8).
// A:[m][k] lda; B:[n][k] ldb=K; res/X: [m][512] bf16 (in-place safe).
__global__ __launch_bounds__(512) void gemmLN(
    const ushort_t* __restrict__ A, const ushort_t* __restrict__ B,
    const float* __restrict__ bias, const ushort_t* __restrict__ res,
    const float* __restrict__ g, const float* __restrict__ bt,
    ushort_t* __restrict__ X, int K, int lda)
{
    __shared__ ushort_t As[2][32 * 64];
    __shared__ ushort_t Bs[2][512 * 64];
    __shared__ float2 pst[8][32];
    __shared__ float2 rmv[32];

    const int t = threadIdx.x;
    const int lane = t & 63, w = t >> 6;        // 8 waves
    const int l16 = lane & 15, quad = lane >> 4;
    const int r8 = lane >> 3;
    const int kg = ((lane & 7) ^ r8) << 3;
    const int wn = w * 64;
    const int m0 = blockIdx.x * 32;
    const int NT = K >> 6;

    f32x4 acc[2][4];
    #pragma unroll
    for (int i = 0; i < 2; i++)
        #pragma unroll
        for (int j = 0; j < 4; j++)
            acc[i][j] = (f32x4){0.f, 0.f, 0.f, 0.f};

    auto STAGE = [&](int kt, int bb) {
        int k0 = kt << 6;
        if (w < 4)
            g2lds16(A + (size_t)(m0 + w * 8 + r8) * lda + k0 + kg,
                    &As[bb][(w * 8) * 64]);
        #pragma unroll
        for (int ii = 0; ii < 8; ii++) {
            int rbase = w * 64 + ii * 8;
            g2lds16(B + (size_t)(rbase + r8) * K + k0 + kg,
                    &Bs[bb][rbase * 64]);
        }
    };

    STAGE(0, 0);
    STAGE(1, 1);

    for (int kt = 0; kt < NT; kt++) {
        const int bb = kt & 1;
        if (kt < NT - 1) {
            if (w < 4) asm volatile("s_waitcnt vmcnt(9)" ::: "memory");
            else       asm volatile("s_waitcnt vmcnt(8)" ::: "memory");
        } else {
            asm volatile("s_waitcnt vmcnt(0)" ::: "memory");
        }
        __builtin_amdgcn_s_barrier();
        asm volatile("" ::: "memory");

        #pragma unroll
        for (int tt = 0; tt < 2; tt++) {
            bf16x8 af[2], bf4[4];
            #pragma unroll
            for (int i = 0; i < 2; i++) {
                int row = i * 16 + l16;
                af[i] = *(const bf16x8*)&As[bb][row * 64 + ((((tt << 2) + quad) ^ (row & 7)) << 3)];
            }
            #pragma unroll
            for (int j = 0; j < 4; j++) {
                int row = wn + j * 16 + l16;
                bf4[j] = *(const bf16x8*)&Bs[bb][row * 64 + ((((tt << 2) + quad) ^ (row & 7)) << 3)];
            }
            #pragma unroll
            for (int i = 0; i < 2; i++)
                #pragma unroll
                for (int j = 0; j < 4; j++)
                    acc[i][j] = __builtin_amdgcn_mfma_f32_16x16x32_bf16(
                        af[i], bf4[j], acc[i][j], 0, 0, 0);
        }

        asm volatile("" ::: "memory");
        __builtin_amdgcn_s_barrier();
        asm volatile("" ::: "memory");
        if (kt + 2 < NT)
            STAGE(kt + 2, bb);
    }

    // ---- epilogue: v = acc + bias + residual; LN over full 512-row ----
    float rs[2][4], rq[2][4];
    #pragma unroll
    for (int i = 0; i < 2; i++)
        #pragma unroll
        for (int r = 0; r < 4; r++) { rs[i][r] = 0.f; rq[i][r] = 0.f; }

    #pragma unroll
    for (int i = 0; i < 2; i++)
        #pragma unroll
        for (int j = 0; j < 4; j++) {
            int n = wn + j * 16 + l16;
            float bvn = bias[n];
            #pragma unroll
            for (int r = 0; r < 4; r++) {
                int row = i * 16 + quad * 4 + r;
                float v = acc[i][j][r] + bvn
                        + bs2f(res[(size_t)(m0 + row) * 512 + n]);
                acc[i][j][r] = v;
                rs[i][r] += v;
                rq[i][r] += v * v;
            }
        }

    #pragma unroll
    for (int i = 0; i < 2; i++)
        #pragma unroll
        for (int r = 0; r < 4; r++) {
            #pragma unroll
            for (int off = 1; off < 16; off <<= 1) {
                rs[i][r] += __shfl_xor(rs[i][r], off);
                rq[i][r] += __shfl_xor(rq[i][r], off);
            }
            if (l16 == 0)
                pst[w][i * 16 + quad * 4 + r] = make_float2(rs[i][r], rq[i][r]);
        }
    __syncthreads();
    if (t < 32) {
        float s = 0.f, q = 0.f;
        #pragma unroll
        for (int wv = 0; wv < 8; wv++) {
            float2 p = pst[wv][t];
            s += p.x; q += p.y;
        }
        float mean = s * (1.f / 512.f);
        float var = q * (1.f / 512.f) - mean * mean;
        rmv[t] = make_float2(mean, rsqrtf(var + 1e-5f));
    }
    __syncthreads();

    #pragma unroll
    for (int i = 0; i < 2; i++)
        #pragma unroll
        for (int j = 0; j < 4; j++) {
            int n = wn + j * 16 + l16;
            float gn = g[n], btn = bt[n];
            #pragma unroll
            for (int r = 0; r < 4; r++) {
                int row = i * 16 + quad * 4 + r;
                float2 mr = rmv[row];
                float o = (acc[i][j][r] - mr.x) * mr.y * gn + btn;
                X[(size_t)(m0 + row) * 512 + n] = f2bs(o);
            }
        }
}

// ---------------------------------------------------------------------------
// Fused flash attention (80 KB LDS, 2 blocks/CU, 2 barriers/kc).
// Q pre-scaled by 1/sqrt(512) in the QKV GEMM -> exp arg is a plain add.
__global__ __launch_bounds__(256) void flash_attn(
    ushort_t* __restrict__ QKV, const ushort_t* __restrict__ Vt,
    const int* __restrict__ tok)
{
    __shared__ ushort_t Qs[128 * 64];
    __shared__ ushort_t Ks[128 * 64];
    __shared__ ushort_t Vts[64 * 128];
    __shared__ ushort_t Ps[128 * 128];

    const int bh = blockIdx.y;
    const int b = bh >> 3, h = bh & 7;
    const int q0 = blockIdx.x * 128;
    const int t = threadIdx.x;
    const int lane = t & 63, w = t >> 6;
    const int l16 = lane & 15, quad = lane >> 4;
    const int wm = w * 32;
    const size_t rowbase = (size_t)b * 512;

    {
        int r8 = lane >> 3;
        int kg = (lane & 7) ^ r8;
        #pragma unroll
        for (int ii = 0; ii < 4; ii++) {
            int rb = w * 32 + ii * 8;
            g2lds16(QKV + (rowbase + q0 + rb + r8) * 1536 + h * 64 + kg * 8,
                    &Qs[rb * 64]);
        }
    }

    f32x4 accO[2][4];
    #pragma unroll
    for (int i = 0; i < 2; i++)
        #pragma unroll
        for (int jv = 0; jv < 4; jv++)
            accO[i][jv] = (f32x4){0.f, 0.f, 0.f, 0.f};
    float lrow[2][4];
    #pragma unroll
    for (int i = 0; i < 2; i++)
        #pragma unroll
        for (int r = 0; r < 4; r++) lrow[i][r] = 0.f;

    for (int kc = 0; kc < 4; kc++) {
        __syncthreads();
        {
            int r8 = lane >> 3;
            int kg = (lane & 7) ^ r8;
            #pragma unroll
            for (int ii = 0; ii < 4; ii++) {
                int rb = w * 32 + ii * 8;
                g2lds16(QKV + (rowbase + kc * 128 + rb + r8) * 1536 + 512 + h * 64 + kg * 8,
                        &Ks[rb * 64]);
            }
        }
        {
            int v4 = lane >> 4;
            #pragma unroll
            for (int ii = 0; ii < 4; ii++) {
                int vb = w * 16 + ii * 4;
                int vd = vb + v4;
                int kg = (lane & 15) ^ (vd & 15);
                g2lds16(Vt + (size_t)bh * 32768 + (size_t)vd * 512 + kc * 128 + kg * 8,
                        &Vts[vb * 128]);
            }
        }
        float maskv[8];
        #pragma unroll
        for (int j = 0; j < 8; j++)
            maskv[j] = (tok[b * 512 + kc * 128 + j * 16 + l16] == 0) ? -1e9f : 0.f;

        __syncthreads();

        f32x4 sacc[2][8];
        #pragma unroll
        for (int i = 0; i < 2; i++)
            #pragma unroll
            for (int j = 0; j < 8; j++)
                sacc[i][j] = (f32x4){0.f, 0.f, 0.f, 0.f};
        #pragma unroll
        for (int tt = 0; tt < 2; tt++) {
            bf16x8 aq[2], bk8[8];
            #pragma unroll
            for (int i = 0; i < 2; i++) {
                int row = wm + i * 16 + l16;
                aq[i] = *(const bf16x8*)&Qs[row * 64 + (((tt << 2) + quad) ^ (row & 7)) * 8];
            }
            #pragma unroll
            for (int j = 0; j < 8; j++) {
                int row = j * 16 + l16;
                bk8[j] = *(const bf16x8*)&Ks[row * 64 + (((tt << 2) + quad) ^ (row & 7)) * 8];
            }
            #pragma unroll
            for (int i = 0; i < 2; i++)
                #pragma unroll
                for (int j = 0; j < 8; j++)
                    sacc[i][j] = __builtin_amdgcn_mfma_f32_16x16x32_bf16(
                        aq[i], bk8[j], sacc[i][j], 0, 0, 0);
        }

        #pragma unroll
        for (int i = 0; i < 2; i++)
            #pragma unroll
            for (int j = 0; j < 8; j++)
                #pragma unroll
                for (int r = 0; r < 4; r++) {
                    float p = __expf(sacc[i][j][r] + maskv[j]);
                    sacc[i][j][r] = p;
                    lrow[i][r] += p;
                }

        #pragma unroll
        for (int i = 0; i < 2; i++)
            #pragma unroll
            for (int j = 0; j < 8; j++) {
                int col = j * 16 + l16;
                int colc = col >> 3, csub = col & 7;
                #pragma unroll
                for (int r = 0; r < 4; r++) {
                    int row = wm + i * 16 + quad * 4 + r;
                    Ps[row * 128 + ((colc ^ (row & 15)) << 3) + csub] = f2bs(sacc[i][j][r]);
                }
            }

        #pragma unroll
        for (int tt = 0; tt < 4; tt++) {
            bf16x8 ap[2], bv8[4];
            #pragma unroll
            for (int i = 0; i < 2; i++) {
                int row = wm + i * 16 + l16;
                ap[i] = *(const bf16x8*)&Ps[row * 128 + ((((tt << 2) + quad)) ^ (row & 15)) * 8];
            }
            #pragma unroll
            for (int jv = 0; jv < 4; jv++) {
                int vd = jv * 16 + l16;
                bv8[jv] = *(const bf16x8*)&Vts[vd * 128 + (((tt << 2) + quad) ^ (vd & 15)) * 8];
            }
            #pragma unroll
            for (int i = 0; i < 2; i++)
                #pragma unroll
                for (int jv = 0; jv < 4; jv++)
                    accO[i][jv] = __builtin_amdgcn_mfma_f32_16x16x32_bf16(
                        ap[i], bv8[jv], accO[i][jv], 0, 0, 0);
        }
    }

    #pragma unroll
    for (int i = 0; i < 2; i++)
        #pragma unroll
        for (int r = 0; r < 4; r++) {
            float s = lrow[i][r];
            #pragma unroll
            for (int off = 1; off < 16; off <<= 1)
                s += __shfl_xor(s, off);
            float inv = 1.f / s;
            int row = q0 + wm + i * 16 + quad * 4 + r;
            #pragma unroll
            for (int jv = 0; jv < 4; jv++) {
                int vd = jv * 16 + l16;
                QKV[(rowbase + row) * 1536 + h * 64 + vd] = f2bs(accO[i][jv][r] * inv);
            }
        }
}

// ---------------------------------------------------------------------------
// prep: all weight transposes (f32 -> bf16, [R][C] -> [C][R]) + concat_bias
// + Fb zero + embed+PE in ONE dispatch (blockIdx ranges). embed: one block
// per s; trig once per (s,d), reused over the 16 batches via LDS tokens.
__global__ __launch_bounds__(256) void prep(
    const float* __restrict__ Wq, const float* __restrict__ Wk,
    const float* __restrict__ Wv, const float* __restrict__ Wo,
    const float* __restrict__ W1, const float* __restrict__ W2,
    const float* __restrict__ bq, const float* __restrict__ bk,
    const float* __restrict__ bv, const int* __restrict__ tok,
    const float* __restrict__ emb,
    __hip_bfloat16* __restrict__ WqkvT, __hip_bfloat16* __restrict__ WoT,
    __hip_bfloat16* __restrict__ W1T, __hip_bfloat16* __restrict__ W2T,
    float* __restrict__ bqkv, float* __restrict__ Fb,
    ushort_t* __restrict__ xb)
{
    const int blk = blockIdx.x;
    const int t = threadIdx.x;

    if (blk < 12288) {                          // ---- weight transposes ----
        __shared__ float tile[32][33];
        const float* in; __hip_bfloat16* out;
        long long inz, outz; int R, Cc, bx, by, bz;
        if (blk < 4096) {                       // Wq/Wk/Wv/Wo: 512x512, 16x16x4
            int seg = blk >> 10, lb = blk & 1023;
            bz = lb >> 8; by = (lb >> 4) & 15; bx = lb & 15;
            R = 512; Cc = 512; inz = 262144;
            if      (seg == 0) { in = Wq; out = WqkvT;          outz = 786432; }
            else if (seg == 1) { in = Wk; out = WqkvT + 262144; outz = 786432; }
            else if (seg == 2) { in = Wv; out = WqkvT + 524288; outz = 786432; }
            else               { in = Wo; out = WoT;            outz = 262144; }
        } else if (blk < 8192) {                // W1: 512x2048, 64x16x4
            int lb = blk - 4096;
            bz = lb >> 10; by = (lb >> 6) & 15; bx = lb & 63;
            R = 512; Cc = 2048; inz = 1048576; outz = 1048576;
            in = W1; out = W1T;
        } else {                                // W2: 2048x512, 16x64x4
            int lb = blk - 8192;
            bz = lb >> 10; by = (lb >> 4) & 63; bx = lb & 15;
            R = 2048; Cc = 512; inz = 1048576; outz = 1048576;
            in = W2; out = W2T;
        }
        in += bz * inz; out += bz * outz;
        int c0 = bx * 32, r0 = by * 32;
        int tx = t & 31, ty = t >> 5;
        #pragma unroll
        for (int i = 0; i < 4; i++)
            tile[ty + i * 8][tx] = in[(size_t)(r0 + ty + i * 8) * Cc + c0 + tx];
        __syncthreads();
        #pragma unroll
        for (int i = 0; i < 4; i++)
            out[(size_t)(c0 + ty + i * 8) * R + r0 + tx] =
                __float2bfloat16(tile[tx][ty + i * 8]);
    } else if (blk < 12312) {                   // ---- concat_bias + Fb=0 ----
        int k = blk - 12288;
        int idx = k * 256 + t;                  // < 6144 = 4*1536
        int l = idx / 1536, n = idx - l * 1536;
        float v = (n < 512) ? bq[l * 512 + n]
                : (n < 1024) ? bk[l * 512 + n - 512]
                             : bv[l * 512 + n - 1024];
        bqkv[idx] = v;
        if (k < 8) Fb[k * 256 + t] = 0.f;
    } else {                                    // ---- embed + PE: 1 block/s --
        int s = blk - 12312;                    // 0..511
        int d0 = t * 2;
        float freq = __expf(-(float)d0 * PE_C);
        float angle = (float)s * freq;
        float sv, cv;
        __sincosf(angle, &sv, &cv);
        __shared__ int toks[16];
        if (t < 16) toks[t] = tok[t * 512 + s];
        __syncthreads();
        #pragma unroll
        for (int b = 0; b < 16; b++) {
            int tk = toks[b];
            float2 e = *(const float2*)&emb[(size_t)tk * 512 + d0];
            ushort2 o;
            o.x = f2bs(e.x + sv);
            o.y = f2bs(e.y + cv);
            *(ushort2*)&xb[((size_t)(b * 512 + s)) * 512 + d0] = o;
        }
    }
}

// ---------------------------------------------------------------------------
// head stage 1 v3: 1024 blocks x 256 k-rows. NO global atomic chains.
__global__ __launch_bounds__(256) void feat_partial(const ushort_t* __restrict__ Xb,
                                                    const float* __restrict__ Wf,
                                                    float* __restrict__ FbP) {
    const int slice = blockIdx.x;           // 0..1023
    const int k0 = slice * 256;
    __shared__ float Xs[16][256];           // 16 KB
    __shared__ float RedW[4][16][128];      // 32 KB: per-wave partials
    const int t = threadIdx.x;

    #pragma unroll
    for (int i = 0; i < 4; i++) {           // 16 b x 256 k bf16 = 1024 ushort4
        int idx = t + i * 256;
        int b = idx >> 6, c4 = (idx & 63) * 4;
        ushort4 u = *(const ushort4*)&Xb[(size_t)b * 262144 + k0 + c4];
        Xs[b][c4 + 0] = bs2f(u.x);
        Xs[b][c4 + 1] = bs2f(u.y);
        Xs[b][c4 + 2] = bs2f(u.z);
        Xs[b][c4 + 3] = bs2f(u.w);
    }
    __syncthreads();

    const int n4 = (t & 31) * 4;
    const int kh = t >> 5;                  // 8 groups x 32 rows
    const int rbase = kh * 32;
    const int wv = t >> 6;                  // wave id (covers kh 2w, 2w+1)
    const float* wp = Wf + (size_t)(k0 + rbase) * 128 + n4;

    float4 acc[16];
    #pragma unroll
    for (int b = 0; b < 16; b++) acc[b] = (float4){0.f, 0.f, 0.f, 0.f};

    #pragma unroll
    for (int q = 0; q < 4; q++) {           // 4 batches of 8 rows in flight
        float4 wvv[8];
        #pragma unroll
        for (int kk = 0; kk < 8; kk++)
            wvv[kk] = *(const float4*)&wp[(size_t)(q * 8 + kk) * 128];
        #pragma unroll
        for (int b = 0; b < 16; b++) {
            float4 x0 = *(const float4*)&Xs[b][rbase + q * 8];
            float4 x1 = *(const float4*)&Xs[b][rbase + q * 8 + 4];
            acc[b].x += x0.x*wvv[0].x + x0.y*wvv[1].x + x0.z*wvv[2].x + x0.w*wvv[3].x
                      + x1.x*wvv[4].x + x1.y*wvv[5].x + x1.z*wvv[6].x + x1.w*wvv[7].x;
            acc[b].y += x0.x*wvv[0].y + x0.y*wvv[1].y + x0.z*wvv[2].y + x0.w*wvv[3].y
                      + x1.x*wvv[4].y + x1.y*wvv[5].y + x1.z*wvv[6].y + x1.w*wvv[7].y;
            acc[b].z += x0.x*wvv[0].z + x0.y*wvv[1].z + x0.z*wvv[2].z + x0.w*wvv[3].z
                      + x1.x*wvv[4].z + x1.y*wvv[5].z + x1.z*wvv[6].z + x1.w*wvv[7].z;
            acc[b].w += x0.x*wvv[0].w + x0.y*wvv[1].w + x0.z*wvv[2].w + x0.w*wvv[3].w
                      + x1.x*wvv[4].w + x1.y*wvv[5].w + x1.z*wvv[6].w + x1.w*wvv[7].w;
        }
    }

    // fold kh pair within wave (lane L and L+32 share n4)
    #pragma unroll
    for (int b = 0; b < 16; b++) {
        acc[b].x += __shfl_xor(acc[b].x, 32);
        acc[b].y += __shfl_xor(acc[b].y, 32);
        acc[b].z += __shfl_xor(acc[b].z, 32);
        acc[b].w += __shfl_xor(acc[b].w, 32);
    }
    if ((t & 63) < 32) {
        #pragma unroll
        for (int b = 0; b < 16; b++)
            *(float4*)&RedW[wv][b][n4] = acc[b];
    }
    __syncthreads();

    #pragma unroll
    for (int i = 0; i < 8; i++) {           // sum 4 wave-partials, store row
        int o = t + i * 256;
        int b = o >> 7, c = o & 127;
        FbP[(size_t)slice * 2048 + o] =
            RedW[0][b][c] + RedW[1][b][c] + RedW[2][b][c] + RedW[3][b][c];
    }
}

// feat_reduce: sum FbP[1024][2048] -> Fb[2048]. Atomic depth 16 per address.
__global__ __launch_bounds__(256) void feat_reduce(const float* __restrict__ FbP,
                                                   float* __restrict__ Fb) {
    int o = blockIdx.x * 256 + threadIdx.x;
    int g0 = blockIdx.y * 64;
    float s = 0.f;
    #pragma unroll
    for (int jj = 0; jj < 64; jj += 8) {
        float v[8];
        #pragma unroll
        for (int u = 0; u < 8; u++)
            v[u] = FbP[(size_t)(g0 + jj + u) * 2048 + o];
        #pragma unroll
        for (int u = 0; u < 8; u++) s += v[u];
    }
    atomicAdd(&Fb[o], s);
}

// out: [0..15]=y_score, [16..31]=y_pred, [32..2079]=features
__global__ __launch_bounds__(256) void head_kernel(const float* __restrict__ feat,
                                                   const float* __restrict__ bfv,
                                                   const float* __restrict__ Wo2,
                                                   const float* __restrict__ bo2,
                                                   float* __restrict__ out) {
    __shared__ float f[2048];
    int t = threadIdx.x;
    for (int i = t; i < 2048; i += 256) {
        float v = feat[i] + bfv[i & 127];
        f[i] = v;
        out[32 + i] = v;
    }
    __syncthreads();
    if (t < 16) {
        float zv = bo2[0];
        for (int n = 0; n < 128; n++) zv = fmaf(f[t * 128 + n], Wo2[n], zv);
        float ys = 1.f / (1.f + expf(-zv));
        out[t] = ys;
        out[16 + t] = rintf(ys);
    }
}

// ---------------------------------------------------------------------------
extern "C" void kernel_launch(void* const* d_in, const int* in_sizes, int n_in,
                              void* d_out, int out_size, void* d_ws, size_t ws_size,
                              hipStream_t stream) {
    const int*   enc  = (const int*)  d_in[0];
    const float* emb  = (const float*)d_in[1];
    const float* Wq   = (const float*)d_in[2];
    const float* bq   = (const float*)d_in[3];
    const float* Wk   = (const float*)d_in[4];
    const float* bk   = (const float*)d_in[5];
    const float* Wv   = (const float*)d_in[6];
    const float* bv   = (const float*)d_in[7];
    const float* Wo   = (const float*)d_in[8];
    const float* bo   = (const float*)d_in[9];
    const float* g1   = (const float*)d_in[10];
    const float* be1  = (const float*)d_in[11];
    const float* W1   = (const float*)d_in[12];
    const float* b1f  = (const float*)d_in[13];
    const float* W2   = (const float*)d_in[14];
    const float* b2f  = (const float*)d_in[15];
    const float* g2   = (const float*)d_in[16];
    const float* be2  = (const float*)d_in[17];
    const float* Wf   = (const float*)d_in[18];
    const float* bf   = (const float*)d_in[19];
    const float* Wout = (const float*)d_in[20];
    const float* bout = (const float*)d_in[21];
    float* out = (float*)d_out;

    // ---- workspace layout (bytes), peak < 119 MB ----
    char* ws = (char*)d_ws;
    float*    FbP  = (float*)    (ws + 0);           // [1024][2048] f32 (tail)
    ushort_t* Xb   = (ushort_t*) (ws + 16777216);    // [8192,512] bf16 activations
    ushort_t* QKV  = (ushort_t*) (ws + 25165824);    // [8192,1536] bf16
    ushort_t* Vt   = (ushort_t*) (ws + 50331648);    // [128][64][512] bf16
    ushort_t* S    = (ushort_t*) (ws + 58720256);    // FFN hidden [8192][2048] bf16
    ushort_t* WqkvT= (ushort_t*) (ws + 92274688);    // [4][1536][512] bf16
    ushort_t* WoT  = (ushort_t*) (ws + 98566144);    // [4][512][512] bf16
    ushort_t* W1T  = (ushort_t*) (ws + 100663296);   // [4][2048][512] bf16
    ushort_t* W2T  = (ushort_t*) (ws + 109051904);   // [4][512][2048] bf16
    float*    bqkv = (float*)    (ws + 117440512);   // [4][1536]
    float*    Fb   = (float*)    (ws + 117465088);   // [16][128]

    typedef __hip_bfloat16 bf16;

    // one dispatch: 12288 transpose + 24 concat + 512 embed (1 block per s)
    prep<<<12824, 256, 0, stream>>>(
        Wq, Wk, Wv, Wo, W1, W2, bq, bk, bv, enc, emb,
        (bf16*)WqkvT, (bf16*)WoT, (bf16*)W1T, (bf16*)W2T, bqkv, Fb, Xb);

    for (int l = 0; l < 4; l++) {
        // QKV: [8192,512]x[512,1536] on 128^2 / 2-blocks-per-CU GEMM;
        // V columns transposed straight to Vt; Q pre-scaled by 1/sqrt(512)
        gemm4t<false, true><<<dim3(12, 64), 256, 0, stream>>>(
            Xb, WqkvT + (size_t)l * 786432, bqkv + l * 1536,
            QKV, Vt, 512, 512, 512, 1536);

        flash_attn<<<dim3(4, 128), 256, 0, stream>>>(QKV, Vt, enc);

        // Wo + bo + residual + LN1 fused -> Xb
        gemmLN<<<256, 512, 0, stream>>>(
            QKV, WoT + (size_t)l * 262144, bo + l * 512, Xb,
            g1 + l * 512, be1 + l * 512, Xb, 512, 1536);

        // FFN1: relu(Xb @ W1T + b1) -> S bf16 (1024 blocks, 2/CU, 2 rounds)
        gemm4t<true, false><<<dim3(16, 64), 256, 0, stream>>>(
            Xb, W1T + (size_t)l * 1048576, b1f + l * 2048,
            S, nullptr, 512, 512, 512, 2048);

        // FFN2 + b2 + residual + LN2 fused -> Xb
        gemmLN<<<256, 512, 0, stream>>>(
            S, W2T + (size_t)l * 1048576, b2f + l * 512, Xb,
            g2 + l * 512, be2 + l * 512, Xb, 2048, 2048);
    }

    feat_partial<<<1024, 256, 0, stream>>>(Xb, Wf, FbP);
    feat_reduce<<<dim3(8, 16), 256, 0, stream>>>(FbP, Fb);
    head_kernel<<<1, 256, 0, stream>>>(Fb, bf, Wout, bout, out);
}

// Round 8
// 886.917 us; speedup vs baseline: 1.0835x; 1.0025x over previous
//
#include <hip/hip_runtime.h>
#include <hip/hip_bf16.h>
#include <math.h>

typedef unsigned short ushort_t;
typedef __attribute__((ext_vector_type(8))) short bf16x8;   // 8 bf16 = 4 VGPRs
typedef __attribute__((ext_vector_type(4))) float f32x4;

#define SCALE_QK 0.04419417382415922f   // 1/sqrt(512)
#define PE_C 0.017988946039015986f      // ln(10000)/512

// ---------------------------------------------------------------------------
__device__ __forceinline__ void g2lds16(const void* g, void* l) {
    __builtin_amdgcn_global_load_lds(
        (const __attribute__((address_space(1))) unsigned int*)g,
        (__attribute__((address_space(3))) unsigned int*)l,
        16, 0, 0);
}
__device__ __forceinline__ ushort_t f2bs(float v) {
    __hip_bfloat16 h = __float2bfloat16(v);
    return *reinterpret_cast<ushort_t*>(&h);
}
__device__ __forceinline__ float bs2f(ushort_t v) {
    return __uint_as_float(((unsigned int)v) << 16);
}

// ---------------------------------------------------------------------------
// 128x128 / 4-wave GEMM, 64 KB LDS double-buffer, 2 blocks/CU. Counted-vmcnt
// pipeline: loads for tile kt+2 issued after the trailing barrier, waited
// with vmcnt(8). Wave-tile 64x64 (MI=4,NJ=4). VT: blocks with n0>=1024
// (QKV's V region) write transposed into vt[bh][vd][s]; VT also pre-scales
// Q cols (n<512) by 1/sqrt(512) so flash's exp arg is a plain add.
template<bool RELU, bool VT>
__global__ __launch_bounds__(256, 2) void gemm4t(
    const ushort_t* __restrict__ A, const ushort_t* __restrict__ B,
    const float* __restrict__ bias, ushort_t* __restrict__ C,
    ushort_t* __restrict__ vt, int K, int lda, int ldb, int ldc)
{
    __shared__ ushort_t As[2][128 * 64];
    __shared__ ushort_t Bs[2][128 * 64];

    const int t = threadIdx.x;
    const int lane = t & 63, w = t >> 6;        // 4 waves
    const int l16 = lane & 15, quad = lane >> 4;
    const int r8 = lane >> 3;
    const int kg = ((lane & 7) ^ r8) << 3;      // swizzled global k-chunk
    const int wm = (w >> 1) * 64;
    const int wn = (w & 1) * 64;
    const int m0 = blockIdx.y * 128, n0 = blockIdx.x * 128;
    const int NT = K >> 6;

    f32x4 acc[4][4];
    #pragma unroll
    for (int i = 0; i < 4; i++)
        #pragma unroll
        for (int j = 0; j < 4; j++)
            acc[i][j] = (f32x4){0.f, 0.f, 0.f, 0.f};

    auto STAGE = [&](int kt, int bb) {
        int k0 = kt << 6;
        #pragma unroll
        for (int ii = 0; ii < 4; ii++) {        // 4 waves x 32 rows = 128
            int rbase = w * 32 + ii * 8;
            g2lds16(A + (size_t)(m0 + rbase + r8) * lda + k0 + kg,
                    &As[bb][rbase * 64]);
            g2lds16(B + (size_t)(n0 + rbase + r8) * ldb + k0 + kg,
                    &Bs[bb][rbase * 64]);
        }
    };

    STAGE(0, 0);
    STAGE(1, 1);

    for (int kt = 0; kt < NT; kt++) {
        const int bb = kt & 1;
        if (kt < NT - 1)
            asm volatile("s_waitcnt vmcnt(8)" ::: "memory");
        else
            asm volatile("s_waitcnt vmcnt(0)" ::: "memory");
        __builtin_amdgcn_s_barrier();
        asm volatile("" ::: "memory");

        #pragma unroll
        for (int tt = 0; tt < 2; tt++) {
            bf16x8 af[4], bf[4];
            #pragma unroll
            for (int i = 0; i < 4; i++) {
                int row = wm + i * 16 + l16;
                af[i] = *(const bf16x8*)&As[bb][row * 64 + ((((tt << 2) + quad) ^ (row & 7)) << 3)];
            }
            #pragma unroll
            for (int j = 0; j < 4; j++) {
                int row = wn + j * 16 + l16;
                bf[j] = *(const bf16x8*)&Bs[bb][row * 64 + ((((tt << 2) + quad) ^ (row & 7)) << 3)];
            }
            #pragma unroll
            for (int i = 0; i < 4; i++)
                #pragma unroll
                for (int j = 0; j < 4; j++)
                    acc[i][j] = __builtin_amdgcn_mfma_f32_16x16x32_bf16(
                        af[i], bf[j], acc[i][j], 0, 0, 0);
        }

        asm volatile("" ::: "memory");
        __builtin_amdgcn_s_barrier();
        asm volatile("" ::: "memory");
        if (kt + 2 < NT)
            STAGE(kt + 2, bb);
    }

    // ---- epilogue ----
    if (VT && n0 >= 1024) {
        #pragma unroll
        for (int i = 0; i < 4; i++) {
            int mbase = m0 + wm + i * 16 + quad * 4;
            int b = mbase >> 9, s = mbase & 511;
            #pragma unroll
            for (int j = 0; j < 4; j++) {
                int n = n0 + wn + j * 16 + l16;
                int hv = n - 1024;
                int h = hv >> 6, vd = hv & 63;
                float bv = bias[n];
                ushort4 pk;
                pk.x = f2bs(acc[i][j][0] + bv);
                pk.y = f2bs(acc[i][j][1] + bv);
                pk.z = f2bs(acc[i][j][2] + bv);
                pk.w = f2bs(acc[i][j][3] + bv);
                *(ushort4*)&vt[((size_t)((b << 3) + h)) * 32768 + (size_t)vd * 512 + s] = pk;
            }
        }
        return;
    }

    #pragma unroll
    for (int i = 0; i < 4; i++)
        #pragma unroll
        for (int j = 0; j < 4; j++) {
            int n = n0 + wn + j * 16 + l16;
            float bv = bias[n];
            #pragma unroll
            for (int r = 0; r < 4; r++) {
                int m = m0 + wm + i * 16 + quad * 4 + r;
                float v = acc[i][j][r] + bv;
                if (RELU) v = fmaxf(v, 0.f);
                if (VT && n < 512) v *= SCALE_QK;   // pre-scale Q for attn
                C[(size_t)m * ldc + n] = f2bs(v);
            }
        }
}

// ---------------------------------------------------------------------------
// Full-row GEMM + bias + residual + LayerNorm fused. BM=32, BN=512; grid =
// M/32 = 256 blocks = 1/CU. 8 waves (512 thr), wave-tile 32x64 -> 2
// waves/SIMD. Counted-vmcnt pipeline; staging: every wave 8 B-rows; waves
// 0-3 also 8 A-rows (+1) -> wave-uniform vmcnt(9)/vmcnt(8).
// A:[m][k] lda; B:[n][k] ldb=K; res/X: [m][512] bf16 (in-place safe).
__global__ __launch_bounds__(512) void gemmLN(
    const ushort_t* __restrict__ A, const ushort_t* __restrict__ B,
    const float* __restrict__ bias, const ushort_t* __restrict__ res,
    const float* __restrict__ g, const float* __restrict__ bt,
    ushort_t* __restrict__ X, int K, int lda)
{
    __shared__ ushort_t As[2][32 * 64];
    __shared__ ushort_t Bs[2][512 * 64];
    __shared__ float2 pst[8][32];
    __shared__ float2 rmv[32];

    const int t = threadIdx.x;
    const int lane = t & 63, w = t >> 6;        // 8 waves
    const int l16 = lane & 15, quad = lane >> 4;
    const int r8 = lane >> 3;
    const int kg = ((lane & 7) ^ r8) << 3;
    const int wn = w * 64;
    const int m0 = blockIdx.x * 32;
    const int NT = K >> 6;

    f32x4 acc[2][4];
    #pragma unroll
    for (int i = 0; i < 2; i++)
        #pragma unroll
        for (int j = 0; j < 4; j++)
            acc[i][j] = (f32x4){0.f, 0.f, 0.f, 0.f};

    auto STAGE = [&](int kt, int bb) {
        int k0 = kt << 6;
        if (w < 4)
            g2lds16(A + (size_t)(m0 + w * 8 + r8) * lda + k0 + kg,
                    &As[bb][(w * 8) * 64]);
        #pragma unroll
        for (int ii = 0; ii < 8; ii++) {
            int rbase = w * 64 + ii * 8;
            g2lds16(B + (size_t)(rbase + r8) * K + k0 + kg,
                    &Bs[bb][rbase * 64]);
        }
    };

    STAGE(0, 0);
    STAGE(1, 1);

    for (int kt = 0; kt < NT; kt++) {
        const int bb = kt & 1;
        if (kt < NT - 1) {
            if (w < 4) asm volatile("s_waitcnt vmcnt(9)" ::: "memory");
            else       asm volatile("s_waitcnt vmcnt(8)" ::: "memory");
        } else {
            asm volatile("s_waitcnt vmcnt(0)" ::: "memory");
        }
        __builtin_amdgcn_s_barrier();
        asm volatile("" ::: "memory");

        #pragma unroll
        for (int tt = 0; tt < 2; tt++) {
            bf16x8 af[2], bf4[4];
            #pragma unroll
            for (int i = 0; i < 2; i++) {
                int row = i * 16 + l16;
                af[i] = *(const bf16x8*)&As[bb][row * 64 + ((((tt << 2) + quad) ^ (row & 7)) << 3)];
            }
            #pragma unroll
            for (int j = 0; j < 4; j++) {
                int row = wn + j * 16 + l16;
                bf4[j] = *(const bf16x8*)&Bs[bb][row * 64 + ((((tt << 2) + quad) ^ (row & 7)) << 3)];
            }
            #pragma unroll
            for (int i = 0; i < 2; i++)
                #pragma unroll
                for (int j = 0; j < 4; j++)
                    acc[i][j] = __builtin_amdgcn_mfma_f32_16x16x32_bf16(
                        af[i], bf4[j], acc[i][j], 0, 0, 0);
        }

        asm volatile("" ::: "memory");
        __builtin_amdgcn_s_barrier();
        asm volatile("" ::: "memory");
        if (kt + 2 < NT)
            STAGE(kt + 2, bb);
    }

    // ---- epilogue: v = acc + bias + residual; LN over full 512-row ----
    float rs[2][4], rq[2][4];
    #pragma unroll
    for (int i = 0; i < 2; i++)
        #pragma unroll
        for (int r = 0; r < 4; r++) { rs[i][r] = 0.f; rq[i][r] = 0.f; }

    #pragma unroll
    for (int i = 0; i < 2; i++)
        #pragma unroll
        for (int j = 0; j < 4; j++) {
            int n = wn + j * 16 + l16;
            float bvn = bias[n];
            #pragma unroll
            for (int r = 0; r < 4; r++) {
                int row = i * 16 + quad * 4 + r;
                float v = acc[i][j][r] + bvn
                        + bs2f(res[(size_t)(m0 + row) * 512 + n]);
                acc[i][j][r] = v;
                rs[i][r] += v;
                rq[i][r] += v * v;
            }
        }

    #pragma unroll
    for (int i = 0; i < 2; i++)
        #pragma unroll
        for (int r = 0; r < 4; r++) {
            #pragma unroll
            for (int off = 1; off < 16; off <<= 1) {
                rs[i][r] += __shfl_xor(rs[i][r], off);
                rq[i][r] += __shfl_xor(rq[i][r], off);
            }
            if (l16 == 0)
                pst[w][i * 16 + quad * 4 + r] = make_float2(rs[i][r], rq[i][r]);
        }
    __syncthreads();
    if (t < 32) {
        float s = 0.f, q = 0.f;
        #pragma unroll
        for (int wv = 0; wv < 8; wv++) {
            float2 p = pst[wv][t];
            s += p.x; q += p.y;
        }
        float mean = s * (1.f / 512.f);
        float var = q * (1.f / 512.f) - mean * mean;
        rmv[t] = make_float2(mean, rsqrtf(var + 1e-5f));
    }
    __syncthreads();

    #pragma unroll
    for (int i = 0; i < 2; i++)
        #pragma unroll
        for (int j = 0; j < 4; j++) {
            int n = wn + j * 16 + l16;
            float gn = g[n], btn = bt[n];
            #pragma unroll
            for (int r = 0; r < 4; r++) {
                int row = i * 16 + quad * 4 + r;
                float2 mr = rmv[row];
                float o = (acc[i][j][r] - mr.x) * mr.y * gn + btn;
                X[(size_t)(m0 + row) * 512 + n] = f2bs(o);
            }
        }
}

// ---------------------------------------------------------------------------
// Fused flash attention (80 KB LDS, 2 blocks/CU, 2 barriers/kc).
// Q pre-scaled by 1/sqrt(512) in the QKV GEMM -> exp arg is a plain add.
// R8: mask loads hoisted out of the kc loop (32 regs, loaded once);
// T5 s_setprio(1) around the QK and PV MFMA clusters (attn-proven +4-7%).
__global__ __launch_bounds__(256) void flash_attn(
    ushort_t* __restrict__ QKV, const ushort_t* __restrict__ Vt,
    const int* __restrict__ tok)
{
    __shared__ ushort_t Qs[128 * 64];
    __shared__ ushort_t Ks[128 * 64];
    __shared__ ushort_t Vts[64 * 128];
    __shared__ ushort_t Ps[128 * 128];

    const int bh = blockIdx.y;
    const int b = bh >> 3, h = bh & 7;
    const int q0 = blockIdx.x * 128;
    const int t = threadIdx.x;
    const int lane = t & 63, w = t >> 6;
    const int l16 = lane & 15, quad = lane >> 4;
    const int wm = w * 32;
    const size_t rowbase = (size_t)b * 512;

    {
        int r8 = lane >> 3;
        int kg = (lane & 7) ^ r8;
        #pragma unroll
        for (int ii = 0; ii < 4; ii++) {
            int rb = w * 32 + ii * 8;
            g2lds16(QKV + (rowbase + q0 + rb + r8) * 1536 + h * 64 + kg * 8,
                    &Qs[rb * 64]);
        }
    }

    // hoisted mask: all 4 kc-chunks' masks once (L2-hot, off critical path)
    float maskv[4][8];
    #pragma unroll
    for (int kc = 0; kc < 4; kc++)
        #pragma unroll
        for (int j = 0; j < 8; j++)
            maskv[kc][j] = (tok[b * 512 + kc * 128 + j * 16 + l16] == 0) ? -1e9f : 0.f;

    f32x4 accO[2][4];
    #pragma unroll
    for (int i = 0; i < 2; i++)
        #pragma unroll
        for (int jv = 0; jv < 4; jv++)
            accO[i][jv] = (f32x4){0.f, 0.f, 0.f, 0.f};
    float lrow[2][4];
    #pragma unroll
    for (int i = 0; i < 2; i++)
        #pragma unroll
        for (int r = 0; r < 4; r++) lrow[i][r] = 0.f;

    for (int kc = 0; kc < 4; kc++) {
        __syncthreads();
        {
            int r8 = lane >> 3;
            int kg = (lane & 7) ^ r8;
            #pragma unroll
            for (int ii = 0; ii < 4; ii++) {
                int rb = w * 32 + ii * 8;
                g2lds16(QKV + (rowbase + kc * 128 + rb + r8) * 1536 + 512 + h * 64 + kg * 8,
                        &Ks[rb * 64]);
            }
        }
        {
            int v4 = lane >> 4;
            #pragma unroll
            for (int ii = 0; ii < 4; ii++) {
                int vb = w * 16 + ii * 4;
                int vd = vb + v4;
                int kg = (lane & 15) ^ (vd & 15);
                g2lds16(Vt + (size_t)bh * 32768 + (size_t)vd * 512 + kc * 128 + kg * 8,
                        &Vts[vb * 128]);
            }
        }

        __syncthreads();

        f32x4 sacc[2][8];
        #pragma unroll
        for (int i = 0; i < 2; i++)
            #pragma unroll
            for (int j = 0; j < 8; j++)
                sacc[i][j] = (f32x4){0.f, 0.f, 0.f, 0.f};
        #pragma unroll
        for (int tt = 0; tt < 2; tt++) {
            bf16x8 aq[2], bk8[8];
            #pragma unroll
            for (int i = 0; i < 2; i++) {
                int row = wm + i * 16 + l16;
                aq[i] = *(const bf16x8*)&Qs[row * 64 + (((tt << 2) + quad) ^ (row & 7)) * 8];
            }
            #pragma unroll
            for (int j = 0; j < 8; j++) {
                int row = j * 16 + l16;
                bk8[j] = *(const bf16x8*)&Ks[row * 64 + (((tt << 2) + quad) ^ (row & 7)) * 8];
            }
            __builtin_amdgcn_s_setprio(1);
            #pragma unroll
            for (int i = 0; i < 2; i++)
                #pragma unroll
                for (int j = 0; j < 8; j++)
                    sacc[i][j] = __builtin_amdgcn_mfma_f32_16x16x32_bf16(
                        aq[i], bk8[j], sacc[i][j], 0, 0, 0);
            __builtin_amdgcn_s_setprio(0);
        }

        #pragma unroll
        for (int i = 0; i < 2; i++)
            #pragma unroll
            for (int j = 0; j < 8; j++)
                #pragma unroll
                for (int r = 0; r < 4; r++) {
                    float p = __expf(sacc[i][j][r] + maskv[kc][j]);
                    sacc[i][j][r] = p;
                    lrow[i][r] += p;
                }

        #pragma unroll
        for (int i = 0; i < 2; i++)
            #pragma unroll
            for (int j = 0; j < 8; j++) {
                int col = j * 16 + l16;
                int colc = col >> 3, csub = col & 7;
                #pragma unroll
                for (int r = 0; r < 4; r++) {
                    int row = wm + i * 16 + quad * 4 + r;
                    Ps[row * 128 + ((colc ^ (row & 15)) << 3) + csub] = f2bs(sacc[i][j][r]);
                }
            }

        #pragma unroll
        for (int tt = 0; tt < 4; tt++) {
            bf16x8 ap[2], bv8[4];
            #pragma unroll
            for (int i = 0; i < 2; i++) {
                int row = wm + i * 16 + l16;
                ap[i] = *(const bf16x8*)&Ps[row * 128 + ((((tt << 2) + quad)) ^ (row & 15)) * 8];
            }
            #pragma unroll
            for (int jv = 0; jv < 4; jv++) {
                int vd = jv * 16 + l16;
                bv8[jv] = *(const bf16x8*)&Vts[vd * 128 + (((tt << 2) + quad) ^ (vd & 15)) * 8];
            }
            __builtin_amdgcn_s_setprio(1);
            #pragma unroll
            for (int i = 0; i < 2; i++)
                #pragma unroll
                for (int jv = 0; jv < 4; jv++)
                    accO[i][jv] = __builtin_amdgcn_mfma_f32_16x16x32_bf16(
                        ap[i], bv8[jv], accO[i][jv], 0, 0, 0);
            __builtin_amdgcn_s_setprio(0);
        }
    }

    #pragma unroll
    for (int i = 0; i < 2; i++)
        #pragma unroll
        for (int r = 0; r < 4; r++) {
            float s = lrow[i][r];
            #pragma unroll
            for (int off = 1; off < 16; off <<= 1)
                s += __shfl_xor(s, off);
            float inv = 1.f / s;
            int row = q0 + wm + i * 16 + quad * 4 + r;
            #pragma unroll
            for (int jv = 0; jv < 4; jv++) {
                int vd = jv * 16 + l16;
                QKV[(rowbase + row) * 1536 + h * 64 + vd] = f2bs(accO[i][jv][r] * inv);
            }
        }
}

// ---------------------------------------------------------------------------
// prep: all weight transposes (f32 -> bf16, [R][C] -> [C][R]) + concat_bias
// + Fb zero + embed+PE in ONE dispatch (blockIdx ranges). embed: one block
// per s; trig once per (s,d), reused over the 16 batches via LDS tokens.
__global__ __launch_bounds__(256) void prep(
    const float* __restrict__ Wq, const float* __restrict__ Wk,
    const float* __restrict__ Wv, const float* __restrict__ Wo,
    const float* __restrict__ W1, const float* __restrict__ W2,
    const float* __restrict__ bq, const float* __restrict__ bk,
    const float* __restrict__ bv, const int* __restrict__ tok,
    const float* __restrict__ emb,
    __hip_bfloat16* __restrict__ WqkvT, __hip_bfloat16* __restrict__ WoT,
    __hip_bfloat16* __restrict__ W1T, __hip_bfloat16* __restrict__ W2T,
    float* __restrict__ bqkv, float* __restrict__ Fb,
    ushort_t* __restrict__ xb)
{
    const int blk = blockIdx.x;
    const int t = threadIdx.x;

    if (blk < 12288) {                          // ---- weight transposes ----
        __shared__ float tile[32][33];
        const float* in; __hip_bfloat16* out;
        long long inz, outz; int R, Cc, bx, by, bz;
        if (blk < 4096) {                       // Wq/Wk/Wv/Wo: 512x512, 16x16x4
            int seg = blk >> 10, lb = blk & 1023;
            bz = lb >> 8; by = (lb >> 4) & 15; bx = lb & 15;
            R = 512; Cc = 512; inz = 262144;
            if      (seg == 0) { in = Wq; out = WqkvT;          outz = 786432; }
            else if (seg == 1) { in = Wk; out = WqkvT + 262144; outz = 786432; }
            else if (seg == 2) { in = Wv; out = WqkvT + 524288; outz = 786432; }
            else               { in = Wo; out = WoT;            outz = 262144; }
        } else if (blk < 8192) {                // W1: 512x2048, 64x16x4
            int lb = blk - 4096;
            bz = lb >> 10; by = (lb >> 6) & 15; bx = lb & 63;
            R = 512; Cc = 2048; inz = 1048576; outz = 1048576;
            in = W1; out = W1T;
        } else {                                // W2: 2048x512, 16x64x4
            int lb = blk - 8192;
            bz = lb >> 10; by = (lb >> 4) & 63; bx = lb & 15;
            R = 2048; Cc = 512; inz = 1048576; outz = 1048576;
            in = W2; out = W2T;
        }
        in += bz * inz; out += bz * outz;
        int c0 = bx * 32, r0 = by * 32;
        int tx = t & 31, ty = t >> 5;
        #pragma unroll
        for (int i = 0; i < 4; i++)
            tile[ty + i * 8][tx] = in[(size_t)(r0 + ty + i * 8) * Cc + c0 + tx];
        __syncthreads();
        #pragma unroll
        for (int i = 0; i < 4; i++)
            out[(size_t)(c0 + ty + i * 8) * R + r0 + tx] =
                __float2bfloat16(tile[tx][ty + i * 8]);
    } else if (blk < 12312) {                   // ---- concat_bias + Fb=0 ----
        int k = blk - 12288;
        int idx = k * 256 + t;                  // < 6144 = 4*1536
        int l = idx / 1536, n = idx - l * 1536;
        float v = (n < 512) ? bq[l * 512 + n]
                : (n < 1024) ? bk[l * 512 + n - 512]
                             : bv[l * 512 + n - 1024];
        bqkv[idx] = v;
        if (k < 8) Fb[k * 256 + t] = 0.f;
    } else {                                    // ---- embed + PE: 1 block/s --
        int s = blk - 12312;                    // 0..511
        int d0 = t * 2;
        float freq = __expf(-(float)d0 * PE_C);
        float angle = (float)s * freq;
        float sv, cv;
        __sincosf(angle, &sv, &cv);
        __shared__ int toks[16];
        if (t < 16) toks[t] = tok[t * 512 + s];
        __syncthreads();
        #pragma unroll
        for (int b = 0; b < 16; b++) {
            int tk = toks[b];
            float2 e = *(const float2*)&emb[(size_t)tk * 512 + d0];
            ushort2 o;
            o.x = f2bs(e.x + sv);
            o.y = f2bs(e.y + cv);
            *(ushort2*)&xb[((size_t)(b * 512 + s)) * 512 + d0] = o;
        }
    }
}

// ---------------------------------------------------------------------------
// head stage 1: 1024 blocks x 256 k-rows. NO global atomic chains.
__global__ __launch_bounds__(256) void feat_partial(const ushort_t* __restrict__ Xb,
                                                    const float* __restrict__ Wf,
                                                    float* __restrict__ FbP) {
    const int slice = blockIdx.x;           // 0..1023
    const int k0 = slice * 256;
    __shared__ float Xs[16][256];           // 16 KB
    __shared__ float RedW[4][16][128];      // 32 KB: per-wave partials
    const int t = threadIdx.x;

    #pragma unroll
    for (int i = 0; i < 4; i++) {           // 16 b x 256 k bf16 = 1024 ushort4
        int idx = t + i * 256;
        int b = idx >> 6, c4 = (idx & 63) * 4;
        ushort4 u = *(const ushort4*)&Xb[(size_t)b * 262144 + k0 + c4];
        Xs[b][c4 + 0] = bs2f(u.x);
        Xs[b][c4 + 1] = bs2f(u.y);
        Xs[b][c4 + 2] = bs2f(u.z);
        Xs[b][c4 + 3] = bs2f(u.w);
    }
    __syncthreads();

    const int n4 = (t & 31) * 4;
    const int kh = t >> 5;                  // 8 groups x 32 rows
    const int rbase = kh * 32;
    const int wv = t >> 6;                  // wave id (covers kh 2w, 2w+1)
    const float* wp = Wf + (size_t)(k0 + rbase) * 128 + n4;

    float4 acc[16];
    #pragma unroll
    for (int b = 0; b < 16; b++) acc[b] = (float4){0.f, 0.f, 0.f, 0.f};

    #pragma unroll
    for (int q = 0; q < 4; q++) {           // 4 batches of 8 rows in flight
        float4 wvv[8];
        #pragma unroll
        for (int kk = 0; kk < 8; kk++)
            wvv[kk] = *(const float4*)&wp[(size_t)(q * 8 + kk) * 128];
        #pragma unroll
        for (int b = 0; b < 16; b++) {
            float4 x0 = *(const float4*)&Xs[b][rbase + q * 8];
            float4 x1 = *(const float4*)&Xs[b][rbase + q * 8 + 4];
            acc[b].x += x0.x*wvv[0].x + x0.y*wvv[1].x + x0.z*wvv[2].x + x0.w*wvv[3].x
                      + x1.x*wvv[4].x + x1.y*wvv[5].x + x1.z*wvv[6].x + x1.w*wvv[7].x;
            acc[b].y += x0.x*wvv[0].y + x0.y*wvv[1].y + x0.z*wvv[2].y + x0.w*wvv[3].y
                      + x1.x*wvv[4].y + x1.y*wvv[5].y + x1.z*wvv[6].y + x1.w*wvv[7].y;
            acc[b].z += x0.x*wvv[0].z + x0.y*wvv[1].z + x0.z*wvv[2].z + x0.w*wvv[3].z
                      + x1.x*wvv[4].z + x1.y*wvv[5].z + x1.z*wvv[6].z + x1.w*wvv[7].z;
            acc[b].w += x0.x*wvv[0].w + x0.y*wvv[1].w + x0.z*wvv[2].w + x0.w*wvv[3].w
                      + x1.x*wvv[4].w + x1.y*wvv[5].w + x1.z*wvv[6].w + x1.w*wvv[7].w;
        }
    }

    // fold kh pair within wave (lane L and L+32 share n4)
    #pragma unroll
    for (int b = 0; b < 16; b++) {
        acc[b].x += __shfl_xor(acc[b].x, 32);
        acc[b].y += __shfl_xor(acc[b].y, 32);
        acc[b].z += __shfl_xor(acc[b].z, 32);
        acc[b].w += __shfl_xor(acc[b].w, 32);
    }
    if ((t & 63) < 32) {
        #pragma unroll
        for (int b = 0; b < 16; b++)
            *(float4*)&RedW[wv][b][n4] = acc[b];
    }
    __syncthreads();

    #pragma unroll
    for (int i = 0; i < 8; i++) {           // sum 4 wave-partials, store row
        int o = t + i * 256;
        int b = o >> 7, c = o & 127;
        FbP[(size_t)slice * 2048 + o] =
            RedW[0][b][c] + RedW[1][b][c] + RedW[2][b][c] + RedW[3][b][c];
    }
}

// ---------------------------------------------------------------------------
// feat_head: merged feat_reduce + head_kernel. 16 blocks (one per batch);
// threads split the 1024 slices in half (t<128: slices 0-511, t>=128:
// 512-1023), LDS pair-sum, then features + wave-reduced dot + sigmoid.
// out: [0..15]=y_score, [16..31]=y_pred, [32..2079]=features
__global__ __launch_bounds__(256) void feat_head(const float* __restrict__ FbP,
                                                 const float* __restrict__ bfv,
                                                 const float* __restrict__ Wo2,
                                                 const float* __restrict__ bo2,
                                                 float* __restrict__ out) {
    const int b = blockIdx.x;               // 0..15
    const int t = threadIdx.x;
    const int c = t & 127;                  // feature within batch
    const int half = t >> 7;                // slice half
    __shared__ float fh[2][128];
    __shared__ float ws[2];

    const int o = b * 128 + c;
    float s = 0.f;
    #pragma unroll
    for (int jj = 0; jj < 512; jj += 8) {
        float v[8];
        #pragma unroll
        for (int u = 0; u < 8; u++)
            v[u] = FbP[(size_t)(half * 512 + jj + u) * 2048 + o];
        #pragma unroll
        for (int u = 0; u < 8; u++) s += v[u];
    }
    fh[half][c] = s;
    __syncthreads();

    if (t < 128) {
        float fv = fh[0][c] + fh[1][c] + bfv[c];
        out[32 + o] = fv;
        fh[0][c] = fv;                      // features for the dot
    }
    __syncthreads();

    // dot(f, Wo2) over 128 features: threads 0-127 contribute, wave-reduce
    float p = (t < 128) ? fh[0][c] * Wo2[c] : 0.f;
    #pragma unroll
    for (int off = 1; off < 64; off <<= 1)
        p += __shfl_xor(p, off);
    if ((t & 63) == 0) ws[t >> 6 == 0 ? 0 : 1] = (t >> 6) < 2 ? p : 0.f;
    if (t == 0 || t == 64) ws[t >> 6] = p;
    __syncthreads();
    if (t == 0) {
        float zv = ws[0] + ws[1] + bo2[0];
        float ys = 1.f / (1.f + expf(-zv));
        out[b] = ys;
        out[16 + b] = rintf(ys);
    }
}

// ---------------------------------------------------------------------------
extern "C" void kernel_launch(void* const* d_in, const int* in_sizes, int n_in,
                              void* d_out, int out_size, void* d_ws, size_t ws_size,
                              hipStream_t stream) {
    const int*   enc  = (const int*)  d_in[0];
    const float* emb  = (const float*)d_in[1];
    const float* Wq   = (const float*)d_in[2];
    const float* bq   = (const float*)d_in[3];
    const float* Wk   = (const float*)d_in[4];
    const float* bk   = (const float*)d_in[5];
    const float* Wv   = (const float*)d_in[6];
    const float* bv   = (const float*)d_in[7];
    const float* Wo   = (const float*)d_in[8];
    const float* bo   = (const float*)d_in[9];
    const float* g1   = (const float*)d_in[10];
    const float* be1  = (const float*)d_in[11];
    const float* W1   = (const float*)d_in[12];
    const float* b1f  = (const float*)d_in[13];
    const float* W2   = (const float*)d_in[14];
    const float* b2f  = (const float*)d_in[15];
    const float* g2   = (const float*)d_in[16];
    const float* be2  = (const float*)d_in[17];
    const float* Wf   = (const float*)d_in[18];
    const float* bf   = (const float*)d_in[19];
    const float* Wout = (const float*)d_in[20];
    const float* bout = (const float*)d_in[21];
    float* out = (float*)d_out;

    // ---- workspace layout (bytes), peak < 119 MB ----
    char* ws = (char*)d_ws;
    float*    FbP  = (float*)    (ws + 0);           // [1024][2048] f32 (tail)
    ushort_t* Xb   = (ushort_t*) (ws + 16777216);    // [8192,512] bf16 activations
    ushort_t* QKV  = (ushort_t*) (ws + 25165824);    // [8192,1536] bf16
    ushort_t* Vt   = (ushort_t*) (ws + 50331648);    // [128][64][512] bf16
    ushort_t* S    = (ushort_t*) (ws + 58720256);    // FFN hidden [8192][2048] bf16
    ushort_t* WqkvT= (ushort_t*) (ws + 92274688);    // [4][1536][512] bf16
    ushort_t* WoT  = (ushort_t*) (ws + 98566144);    // [4][512][512] bf16
    ushort_t* W1T  = (ushort_t*) (ws + 100663296);   // [4][2048][512] bf16
    ushort_t* W2T  = (ushort_t*) (ws + 109051904);   // [4][512][2048] bf16
    float*    bqkv = (float*)    (ws + 117440512);   // [4][1536]
    float*    Fb   = (float*)    (ws + 117465088);   // [16][128] (unused now)

    typedef __hip_bfloat16 bf16;

    // one dispatch: 12288 transpose + 24 concat + 512 embed (1 block per s)
    prep<<<12824, 256, 0, stream>>>(
        Wq, Wk, Wv, Wo, W1, W2, bq, bk, bv, enc, emb,
        (bf16*)WqkvT, (bf16*)WoT, (bf16*)W1T, (bf16*)W2T, bqkv, Fb, Xb);

    for (int l = 0; l < 4; l++) {
        // QKV: [8192,512]x[512,1536] on 128^2 / 2-blocks-per-CU GEMM;
        // V columns transposed straight to Vt; Q pre-scaled by 1/sqrt(512)
        gemm4t<false, true><<<dim3(12, 64), 256, 0, stream>>>(
            Xb, WqkvT + (size_t)l * 786432, bqkv + l * 1536,
            QKV, Vt, 512, 512, 512, 1536);

        flash_attn<<<dim3(4, 128), 256, 0, stream>>>(QKV, Vt, enc);

        // Wo + bo + residual + LN1 fused -> Xb
        gemmLN<<<256, 512, 0, stream>>>(
            QKV, WoT + (size_t)l * 262144, bo + l * 512, Xb,
            g1 + l * 512, be1 + l * 512, Xb, 512, 1536);

        // FFN1: relu(Xb @ W1T + b1) -> S bf16 (1024 blocks, 2/CU, 2 rounds)
        gemm4t<true, false><<<dim3(16, 64), 256, 0, stream>>>(
            Xb, W1T + (size_t)l * 1048576, b1f + l * 2048,
            S, nullptr, 512, 512, 512, 2048);

        // FFN2 + b2 + residual + LN2 fused -> Xb
        gemmLN<<<256, 512, 0, stream>>>(
            S, W2T + (size_t)l * 1048576, b2f + l * 512, Xb,
            g2 + l * 512, be2 + l * 512, Xb, 2048, 2048);
    }

    feat_partial<<<1024, 256, 0, stream>>>(Xb, Wf, FbP);
    feat_head<<<16, 256, 0, stream>>>(FbP, bf, Wout, bout, out);
}